// Round 15
// baseline (490.081 us; speedup 1.0000x reference)
//
#include <hip/hip_runtime.h>

// DGraphDTA r30 = r29 (459.9us, bf16 activations) + 512-thread fused blocks.
// r29 post-mortem: bytes halved (FETCH 221->104MB), L3 126->87us but BW fell
// to 1.76 TB/s -- below the pattern's ~2.5-3.9 service rate -> latency-bound
// again. r25's 512-thread test was null ONLY because fp32 was byte-pinned;
// in the latency regime more waves convert to throughput. Same tile/LDS
// (3 blk/CU), 512 thr = 24 waves/CU gathering; phase 2 = 2 row-halves x
// 4 col-quarters (r25-verified). Bitwise-identical output to r29.

static inline int cdiv(int a, int b) { return (a + b - 1) / b; }

// ---------------- bf16 helpers ----------------

__device__ __forceinline__ unsigned short f2bf(float x) {
    unsigned u = __float_as_uint(x);
    u += 0x7FFFu + ((u >> 16) & 1u);   // RNE
    return (unsigned short)(u >> 16);
}
__device__ __forceinline__ float bf2f(unsigned short h) {
    return __uint_as_float((unsigned)h << 16);
}

// ---------------- fused CSR build ----------------

__global__ void deg2_kernel(const int* __restrict__ dstA, int* __restrict__ degA, int EA,
                            const int* __restrict__ dstB, int* __restrict__ degB, int EB) {
    int t = blockIdx.x * blockDim.x + threadIdx.x;
    if (t < EA) { atomicAdd(&degA[dstA[t]], 1); return; }
    t -= EA;
    if (t < EB) atomicAdd(&degB[dstB[t]], 1);
}

__global__ void degsum2_kernel(const int* __restrict__ deg_p, int NP, int nbp,
                               const int* __restrict__ deg_m, int NM, int* __restrict__ bsum) {
    __shared__ int s[256];
    int b = blockIdx.x, tid = threadIdx.x;
    const int* deg; int N, bi;
    if (b < nbp) { deg = deg_p; N = NP; bi = b; }
    else         { deg = deg_m; N = NM; bi = b - nbp; }
    int t = bi * 256 + tid;
    s[tid] = (t < N) ? deg[t] : 0;
    __syncthreads();
    for (int off = 128; off > 0; off >>= 1) {
        if (tid < off) s[tid] += s[tid + off];
        __syncthreads();
    }
    if (tid == 0) bsum[b] = s[0];
}

__global__ void scan2_kernel(int* __restrict__ bsum, int nbp, int nbm) {
    __shared__ int s[512];
    int tid = threadIdx.x;
    int total = nbp + nbm;
    int v = (tid < total) ? bsum[tid] : 0;
    bool isMol = (tid >= nbp);
    s[tid] = v;
    __syncthreads();
    for (int off = 1; off < 512; off <<= 1) {
        int x = 0;
        if (tid >= off) {
            int src = tid - off;
            if ((src >= nbp) == isMol) x = s[src];
        }
        __syncthreads();
        s[tid] += x;
        __syncthreads();
    }
    if (tid < total) bsum[tid] = s[tid] - v;
}

__global__ void alloc_scan2_kernel(const int* __restrict__ deg_p, int* rs_p, int* fc_p, float* n_p,
                                   int NP, int nbp,
                                   const int* __restrict__ deg_m, int* rs_m, int* fc_m, float* n_m,
                                   int NM, const int* __restrict__ bsum) {
    __shared__ int s[256];
    int b = blockIdx.x, tid = threadIdx.x;
    const int* deg; int* rs; int* fc; float* nrm; int N, bi;
    if (b < nbp) { deg = deg_p; rs = rs_p; fc = fc_p; nrm = n_p; N = NP; bi = b; }
    else         { deg = deg_m; rs = rs_m; fc = fc_m; nrm = n_m; N = NM; bi = b - nbp; }
    int t = bi * 256 + tid;
    int v = (t < N) ? deg[t] : 0;
    s[tid] = v;
    __syncthreads();
    for (int off = 1; off < 256; off <<= 1) {
        int x = (tid >= off) ? s[tid - off] : 0;
        __syncthreads();
        s[tid] += x;
        __syncthreads();
    }
    if (t < N) {
        int start = bsum[b] + s[tid] - v;
        rs[t] = start;
        fc[t] = start;
        nrm[t] = rsqrtf((float)v + 1.0f);
    }
}

__global__ void fill2_kernel(const int* srcA, const int* dstA, int* fcA, int* esA, int EA,
                             const int* srcB, const int* dstB, int* fcB, int* esB, int EB) {
    int t = blockIdx.x * blockDim.x + threadIdx.x;
    if (t < EA) { int p = atomicAdd(&fcA[dstA[t]], 1); esA[p] = srcA[t]; return; }
    t -= EA;
    if (t < EB) { int p = atomicAdd(&fcB[dstB[t]], 1); esB[p] = srcB[t]; }
}

__device__ __forceinline__ void gs_body(const int* batch, int* gs, int t, int N, int B) {
    int b = batch[t];
    int bp = (t == 0) ? -1 : batch[t - 1];
    for (int g = bp + 1; g <= b; ++g) gs[g] = t;
    if (t == N - 1) for (int g = b + 1; g <= B; ++g) gs[g] = N;
}

__global__ void gs2_kernel(const int* batchA, int* gsA, int NA,
                           const int* batchB, int* gsB, int NB, int B) {
    int t = blockIdx.x * blockDim.x + threadIdx.x;
    if (t < NA) { gs_body(batchA, gsA, t, NA, B); return; }
    t -= NA;
    if (t < NB) gs_body(batchB, gsB, t, NB, B);
}

// pad + convert x0 to bf16 rows
__global__ void pad2_kernel(const float* xA, unsigned short* yA, int NA, int FA, int SA,
                            const float* xB, unsigned short* yB, int NB, int FB, int SB) {
    int t = blockIdx.x * blockDim.x + threadIdx.x;
    if (t < NA * SA) {
        int r = t / SA, j = t - r * SA;
        yA[t] = (j < FA) ? f2bf(xA[(size_t)r * FA + j]) : (unsigned short)0;
        return;
    }
    t -= NA * SA;
    if (t < NB * SB) {
        int r = t / SB, j = t - r * SB;
        yB[t] = (j < FB) ? f2bf(xB[(size_t)r * FB + j]) : (unsigned short)0;
    }
}

// ---------------- W pack: transpose + pad + bf16 hi/lo split ----------------
//   seg offW    Kp   Np   K   N     offB
//   p1  0       64   64   54  54    0
//   p2  4096    64   128  54  108   64
//   p3  12288   128  256  108 216   192
//   m1  45056   96   128  78  78    448
//   m2  57344   128  192  78  156   576
//   m3  81920   192  320  156 312   768   (totals: 143360 W, 1088 bias)

__global__ void wpack_kernel(
    const float* __restrict__ w1p, const float* __restrict__ w2p, const float* __restrict__ w3p,
    const float* __restrict__ b1p, const float* __restrict__ b2p, const float* __restrict__ b3p,
    const float* __restrict__ w1m, const float* __restrict__ w2m, const float* __restrict__ w3m,
    const float* __restrict__ b1m, const float* __restrict__ b2m, const float* __restrict__ b3m,
    unsigned short* __restrict__ Wh, unsigned short* __restrict__ Wl, float* __restrict__ Bp)
{
    int t = blockIdx.x * 256 + threadIdx.x;
    if (t < 143360) {
        const float* w; int Kp, K, N, off;
        if      (t <  4096) { w = w1p; Kp = 64;  K = 54;  N = 54;  off = 0; }
        else if (t < 12288) { w = w2p; Kp = 64;  K = 54;  N = 108; off = 4096; }
        else if (t < 45056) { w = w3p; Kp = 128; K = 108; N = 216; off = 12288; }
        else if (t < 57344) { w = w1m; Kp = 96;  K = 78;  N = 78;  off = 45056; }
        else if (t < 81920) { w = w2m; Kp = 128; K = 78;  N = 156; off = 57344; }
        else                { w = w3m; Kp = 192; K = 156; N = 312; off = 81920; }
        int local = t - off;
        int n = local / Kp, k = local - n * Kp;
        float v = (k < K && n < N) ? w[(size_t)k * N + n] : 0.0f;
        unsigned short h = f2bf(v);
        Wh[t] = h;
        Wl[t] = f2bf(v - bf2f(h));
        return;
    }
    int u = t - 143360;
    if (u < 1088) {
        const float* b; int N, off;
        if      (u <  64) { b = b1p; N = 54;  off = 0; }
        else if (u < 192) { b = b2p; N = 108; off = 64; }
        else if (u < 448) { b = b3p; N = 216; off = 192; }
        else if (u < 576) { b = b1m; N = 78;  off = 448; }
        else if (u < 768) { b = b2m; N = 156; off = 576; }
        else              { b = b3m; N = 312; off = 768; }
        int n = u - off;
        Bp[u] = (n < N) ? b[n] : 0.0f;
    }
}

// ---------------- fused gather+GEMM (64 rows x full Np, 512 thr, bf16 acts) ----------------

typedef __attribute__((ext_vector_type(8))) short s16x8;
typedef __attribute__((ext_vector_type(4))) float f32x4_t;

template <int KP, int NPo>
__device__ __forceinline__ void fused_body(
    const unsigned short* __restrict__ X, const float* __restrict__ norm,
    const int* __restrict__ rs, const int* __restrict__ deg, const int* __restrict__ es,
    const unsigned short* __restrict__ Wh, const unsigned short* __restrict__ Wl,
    const float* __restrict__ bias, unsigned short* __restrict__ out,
    int brow, unsigned short* Ah, unsigned short* Al)
{
    constexpr int LDK = KP + 8;   // shorts; row offset = 4 banks mod 32 -> <=2-way
    constexpr int UV  = KP / 8;   // ushort8 units per row
    constexpr int UV2 = UV / 2;   // 2-unit pieces per row
    constexpr int NF  = NPo / 64; // N-frags per wave quarter
    const int tid = threadIdx.x;

    // ---- phase 1: aggregate 64 bf16 rows -> fp32 -> bf16 hi/lo in LDS ----
    const s16x8* xv = reinterpret_cast<const s16x8*>(X);
    for (int p = tid; p < 64 * UV2; p += 512) {
        int r = p / UV2, q = p - r * UV2;
        int n = brow + r;
        size_t base = (size_t)n * UV;
        float nn = norm[n];
        s16x8 u0 = xv[base + q], u1 = xv[base + q + UV2];
        float a0[8], a1[8];
#pragma unroll
        for (int k = 0; k < 8; ++k) {
            a0[k] = nn * bf2f((unsigned short)u0[k]);
            a1[k] = nn * bf2f((unsigned short)u1[k]);
        }
        int rsv = rs[n], d = deg[n];
        const int* e = es + rsv;
        int i = 0;
        for (; i + 2 <= d; i += 2) {
            int s0 = e[i], s1 = e[i + 1];
            float n0 = norm[s0], n1 = norm[s1];
            size_t b0 = (size_t)s0 * UV, b1 = (size_t)s1 * UV;
            s16x8 v00 = xv[b0 + q], v01 = xv[b0 + q + UV2];
            s16x8 v10 = xv[b1 + q], v11 = xv[b1 + q + UV2];
#pragma unroll
            for (int k = 0; k < 8; ++k) {
                a0[k] = fmaf(n0, bf2f((unsigned short)v00[k]), a0[k]);
                a1[k] = fmaf(n0, bf2f((unsigned short)v01[k]), a1[k]);
            }
#pragma unroll
            for (int k = 0; k < 8; ++k) {
                a0[k] = fmaf(n1, bf2f((unsigned short)v10[k]), a0[k]);
                a1[k] = fmaf(n1, bf2f((unsigned short)v11[k]), a1[k]);
            }
        }
        if (i < d) {
            int s0 = e[i];
            float n0 = norm[s0];
            size_t b0 = (size_t)s0 * UV;
            s16x8 v00 = xv[b0 + q], v01 = xv[b0 + q + UV2];
#pragma unroll
            for (int k = 0; k < 8; ++k) {
                a0[k] = fmaf(n0, bf2f((unsigned short)v00[k]), a0[k]);
                a1[k] = fmaf(n0, bf2f((unsigned short)v01[k]), a1[k]);
            }
        }
        s16x8 h0, l0, h1, l1;
#pragma unroll
        for (int k = 0; k < 8; ++k) {
            unsigned short h = f2bf(a0[k]);
            h0[k] = (short)h; l0[k] = (short)f2bf(a0[k] - bf2f(h));
            unsigned short g = f2bf(a1[k]);
            h1[k] = (short)g; l1[k] = (short)f2bf(a1[k] - bf2f(g));
        }
        *reinterpret_cast<s16x8*>(&Ah[r * LDK + 8 * q]) = h0;
        *reinterpret_cast<s16x8*>(&Ah[r * LDK + 8 * (q + UV2)]) = h1;
        *reinterpret_cast<s16x8*>(&Al[r * LDK + 8 * q]) = l0;
        *reinterpret_cast<s16x8*>(&Al[r * LDK + 8 * (q + UV2)]) = l1;
    }
    __syncthreads();

    // ---- phase 2: 8 waves = 2 row-halves x 4 col-quarters ----
    const int wave = tid >> 6, lane = tid & 63;
    const int wr = wave >> 2, wq = wave & 3;
    const int l15 = lane & 15, l4 = lane >> 4;
    const int nc0 = wq * (NPo / 4);

    f32x4_t acc[2][NF];
#pragma unroll
    for (int mf = 0; mf < 2; ++mf)
#pragma unroll
        for (int nf = 0; nf < NF; ++nf)
            acc[mf][nf] = (f32x4_t){0.f, 0.f, 0.f, 0.f};

    for (int k0 = 0; k0 < KP; k0 += 32) {
        s16x8 ah[2], al[2];
#pragma unroll
        for (int mf = 0; mf < 2; ++mf) {
            int r = wr * 32 + mf * 16 + l15;
            ah[mf] = *reinterpret_cast<const s16x8*>(&Ah[r * LDK + k0 + l4 * 8]);
            al[mf] = *reinterpret_cast<const s16x8*>(&Al[r * LDK + k0 + l4 * 8]);
        }
#pragma unroll
        for (int nf = 0; nf < NF; ++nf) {
            size_t wb = (size_t)(nc0 + nf * 16 + l15) * KP + k0 + l4 * 8;
            s16x8 bh = *reinterpret_cast<const s16x8*>(&Wh[wb]);
            s16x8 bl = *reinterpret_cast<const s16x8*>(&Wl[wb]);
#pragma unroll
            for (int mf = 0; mf < 2; ++mf) {
                acc[mf][nf] = __builtin_amdgcn_mfma_f32_16x16x32_bf16(ah[mf], bh, acc[mf][nf], 0, 0, 0);
                acc[mf][nf] = __builtin_amdgcn_mfma_f32_16x16x32_bf16(ah[mf], bl, acc[mf][nf], 0, 0, 0);
                acc[mf][nf] = __builtin_amdgcn_mfma_f32_16x16x32_bf16(al[mf], bh, acc[mf][nf], 0, 0, 0);
            }
        }
    }

    // epilogue: C frag col = lane&15, row = (lane>>4)*4 + reg; store bf16
#pragma unroll
    for (int mf = 0; mf < 2; ++mf) {
#pragma unroll
        for (int reg = 0; reg < 4; ++reg) {
            int gm = brow + wr * 32 + mf * 16 + l4 * 4 + reg;
            float sc = norm[gm];
#pragma unroll
            for (int nf = 0; nf < NF; ++nf) {
                int gn = nc0 + nf * 16 + l15;
                float v = fmaxf(fmaf(sc, acc[mf][nf][reg], bias[gn]), 0.f);
                out[(size_t)gm * NPo + gn] = f2bf(v);
            }
        }
    }
}

template <int KPA, int NPA, int KPB, int NPB>
__global__ __launch_bounds__(512) void fused_gcn2_kernel(
    const unsigned short* XA, const float* nA, const int* rsA, const int* dA, const int* esA,
    const unsigned short* WhA, const unsigned short* WlA, const float* bsA,
    unsigned short* oA, int nbA,
    const unsigned short* XB, const float* nB, const int* rsB, const int* dB, const int* esB,
    const unsigned short* WhB, const unsigned short* WlB, const float* bsB,
    unsigned short* oB)
{
    constexpr int KMAX = (KPA > KPB ? KPA : KPB);
    __shared__ __align__(16) unsigned short Ah[64 * (KMAX + 8)];
    __shared__ __align__(16) unsigned short Al[64 * (KMAX + 8)];
    int bid = blockIdx.x;
    if (bid < nbA)
        fused_body<KPA, NPA>(XA, nA, rsA, dA, esA, WhA, WlA, bsA, oA, bid * 64, Ah, Al);
    else
        fused_body<KPB, NPB>(XB, nB, rsB, dB, esB, WhB, WlB, bsB, oB, (bid - nbA) * 64, Ah, Al);
}

// ---------------- vec helpers (fc path, fp32) ----------------

__device__ __forceinline__ float4 vmad(float s, float4 a, float4 b) {
    return make_float4(fmaf(s, a.x, b.x), fmaf(s, a.y, b.y), fmaf(s, a.z, b.z), fmaf(s, a.w, b.w));
}

// ---------------- FC (M=256): M-reuse + deep split-K ----------------

template <bool RELU, int MR, int JT>
__device__ __forceinline__ void fc_body(
    const float* __restrict__ X, const float* __restrict__ W,
    const float* __restrict__ bias, float* __restrict__ out,
    int K, int N, int out_stride, int out_off, int bx, int by, float* smem)
{
    constexpr int TJ = JT / 4;
    constexpr int SK = 256 / TJ;
    float* Xs = smem;
    float* red = smem + MR * K;

    const int tid = threadIdx.x;
    const int m0 = by * MR;
    const int j0 = bx * JT;

    for (int idx = tid; idx < MR * K; idx += 256) {
        int r = idx / K, k = idx - r * K;
        Xs[idx] = X[(size_t)(m0 + r) * K + k];
    }
    __syncthreads();

    const int tj = tid % TJ;
    const int s  = tid / TJ;
    const int chunk = (K + SK - 1) / SK;
    const int kb = s * chunk;
    const int ke = min(K, kb + chunk);

    const float4* w4 = reinterpret_cast<const float4*>(W + j0) + tj;
    const int wstride = N >> 2;

    float4 acc[MR];
#pragma unroll
    for (int r = 0; r < MR; ++r) acc[r] = make_float4(0.f, 0.f, 0.f, 0.f);
    for (int k = kb; k < ke; ++k) {
        float4 w = w4[(size_t)k * wstride];
#pragma unroll
        for (int r = 0; r < MR; ++r)
            acc[r] = vmad(Xs[r * K + k], w, acc[r]);
    }
#pragma unroll
    for (int r = 0; r < MR; ++r) {
        float* rr = red + ((s * MR + r) * JT) + tj * 4;
        rr[0] = acc[r].x; rr[1] = acc[r].y; rr[2] = acc[r].z; rr[3] = acc[r].w;
    }
    __syncthreads();

    for (int o = tid; o < MR * JT; o += 256) {
        int r = o / JT, j = o - r * JT;
        float v = 0.f;
#pragma unroll
        for (int ss = 0; ss < SK; ++ss) v += red[(ss * MR + r) * JT + j];
        v += bias[j0 + j];
        if (RELU) v = fmaxf(v, 0.0f);
        out[(size_t)(m0 + r) * out_stride + out_off + j0 + j] = v;
    }
}

template <bool RELU, int MR, int JT>
__global__ __launch_bounds__(256) void fc2_kernel(
    const float* XA, const float* WA, const float* bA, float* oA,
    int KA, int NA, int osA, int ooA, int nbA, int gxA,
    const float* XB, const float* WB, const float* bB, float* oB,
    int KB, int NB, int osB, int ooB, int gxB)
{
    extern __shared__ float smem[];
    int bid = blockIdx.x;
    if (bid < nbA) {
        fc_body<RELU, MR, JT>(XA, WA, bA, oA, KA, NA, osA, ooA, bid % gxA, bid / gxA, smem);
    } else {
        bid -= nbA;
        fc_body<RELU, MR, JT>(XB, WB, bB, oB, KB, NB, osB, ooB, bid % gxB, bid / gxB, smem);
    }
}

template <bool RELU, int MR, int JT>
__global__ __launch_bounds__(256) void fc_kernel(
    const float* X, const float* W, const float* b, float* o,
    int K, int N, int out_stride, int out_off)
{
    extern __shared__ float smem[];
    fc_body<RELU, MR, JT>(X, W, b, o, K, N, out_stride, out_off, blockIdx.x, blockIdx.y, smem);
}

// final layer: one block per row, 256 threads, LDS tree reduce (K=512)
__global__ __launch_bounds__(256) void matvec_kernel(
    const float* __restrict__ X, const float* __restrict__ W,
    const float* __restrict__ bias, float* __restrict__ out, int K)
{
    __shared__ float red[256];
    const int m = blockIdx.x;
    const int tid = threadIdx.x;
    float acc = 0.f;
    for (int k = tid; k < K; k += 256) acc = fmaf(X[(size_t)m * K + k], W[k], acc);
    red[tid] = acc;
    __syncthreads();
    for (int w = 128; w >= 64; w >>= 1) {
        if (tid < w) red[tid] += red[tid + w];
        __syncthreads();
    }
    if (tid < 64) {
        float v = red[tid];
        for (int off = 32; off > 0; off >>= 1) v += __shfl_down(v, off, 64);
        if (tid == 0) out[m] = v + bias[0];
    }
}

// ---------------- row-parallel pooling (block per graph, bf16 input) ----------------
// pro: U=27 ushort8 units (216 elems), stride 32 units; mol: U=39, stride 40.

__global__ __launch_bounds__(1024) void pool4_kernel(
    const unsigned short* __restrict__ xA, const int* __restrict__ gsA, float* __restrict__ poolA,
    const unsigned short* __restrict__ xB, const int* __restrict__ gsB, float* __restrict__ poolB)
{
    __shared__ float red[1024 * 8];
    const int b = blockIdx.x, tid = threadIdx.x;
    const s16x8* xv; const int* gs; float* pool; int U, sv, g;
    if (b < 256) { xv = (const s16x8*)xA; gs = gsA; pool = poolA; U = 27; sv = 32; g = b; }
    else         { xv = (const s16x8*)xB; gs = gsB; pool = poolB; U = 39; sv = 40; g = b - 256; }
    const int s = gs[g], c = gs[g + 1] - s;
    const int nrg = 1024 / U;
    const int jv = tid % U, rg = tid / U;

    float a[8] = {0.f, 0.f, 0.f, 0.f, 0.f, 0.f, 0.f, 0.f};
    if (rg < nrg) {
        for (int i = rg; i < c; i += nrg) {
            s16x8 u = xv[(size_t)(s + i) * sv + jv];
#pragma unroll
            for (int k = 0; k < 8; ++k) a[k] += bf2f((unsigned short)u[k]);
        }
    }
#pragma unroll
    for (int k = 0; k < 8; ++k) red[tid * 8 + k] = a[k];
    __syncthreads();
    if (rg == 0) {
        for (int q = 1; q < nrg; ++q) {
            const float* rr = &red[(q * U + jv) * 8];
#pragma unroll
            for (int k = 0; k < 8; ++k) a[k] += rr[k];
        }
        const float fc_ = (float)max(c, 1);
        float* po = &pool[(size_t)g * (U * 8) + jv * 8];
#pragma unroll
        for (int k = 0; k < 8; ++k) po[k] = a[k] / fc_;
    }
}

extern "C" void kernel_launch(void* const* d_in, const int* in_sizes, int n_in,
                              void* d_out, int out_size, void* d_ws, size_t ws_size,
                              hipStream_t stream) {
    const float* mol_x     = (const float*)d_in[0];
    const int*   mol_ei    = (const int*)  d_in[1];
    const int*   mol_batch = (const int*)  d_in[2];
    const float* pro_x     = (const float*)d_in[3];
    const int*   pro_ei    = (const int*)  d_in[4];
    const int*   pro_batch = (const int*)  d_in[5];
    const float* mw1 = (const float*)d_in[6],  * mb1 = (const float*)d_in[7];
    const float* mw2 = (const float*)d_in[8],  * mb2 = (const float*)d_in[9];
    const float* mw3 = (const float*)d_in[10], * mb3 = (const float*)d_in[11];
    const float* mfw1 = (const float*)d_in[12], * mfb1 = (const float*)d_in[13];
    const float* mfw2 = (const float*)d_in[14], * mfb2 = (const float*)d_in[15];
    const float* pw1 = (const float*)d_in[16], * pb1 = (const float*)d_in[17];
    const float* pw2 = (const float*)d_in[18], * pb2 = (const float*)d_in[19];
    const float* pw3 = (const float*)d_in[20], * pb3 = (const float*)d_in[21];
    const float* pfw1 = (const float*)d_in[22], * pfb1 = (const float*)d_in[23];
    const float* pfw2 = (const float*)d_in[24], * pfb2 = (const float*)d_in[25];
    const float* fc1w = (const float*)d_in[26], * fc1b = (const float*)d_in[27];
    const float* fc2w = (const float*)d_in[28], * fc2b = (const float*)d_in[29];
    const float* outw = (const float*)d_in[30], * outb = (const float*)d_in[31];
    float* out = (float*)d_out;

    // ---- dims ----
    const int NP = 76800, EP = 768000;
    const int NM = 10240, EM = 40960;
    const int NBP = cdiv(NP, 256), NBM = cdiv(NM, 256);  // 300, 40
    // padded dims: pro Kp {64,64,128} Np {64,128,256}; mol Kp {96,128,192} Np {128,192,320}

    // ---- workspace layout (bf16 activations) ----
    unsigned short* Pp = (unsigned short*)d_ws;       // 76800*256
    unsigned short* Rp = Pp + (size_t)76800 * 256;    // 76800*128
    unsigned short* Pm = Rp + (size_t)76800 * 128;    // 10240*320
    unsigned short* Rm = Pm + (size_t)10240 * 320;    // 10240*192
    unsigned short* WpkH = Rm + (size_t)10240 * 192;  // 143360
    unsigned short* WpkL = WpkH + 143360;             // 143360
    float* Bpk    = (float*)(WpkL + 143360);          // 1088
    float* norm_p = Bpk + 1088;                       // 76800
    float* norm_m = norm_p + NP;                      // 10240
    float* pool_p = norm_m + NM;                      // 256*216
    float* pool_m = pool_p + 256 * 216;               // 256*312
    float* fcb_p  = pool_m + 256 * 312;               // 256*1024
    float* fcb_m  = fcb_p + 256 * 1024;               // 256*1024
    float* xc     = fcb_m + 256 * 1024;               // 256*256
    float* hb1    = xc + 256 * 256;                   // 256*1024
    float* hb2    = hb1 + 256 * 1024;                 // 256*512
    int* ibase    = (int*)(hb2 + 256 * 512);
    int* deg_p = ibase;                        // 76800 (memset region start)
    int* deg_m = deg_p + NP;                   // 10240
    int* rs_p  = deg_m + NM;                   // 76800
    int* fc_p  = rs_p + NP;                    // 76800
    int* es_p  = fc_p + NP;                    // 768000
    int* rs_m  = es_p + EP;                    // 10240
    int* fc_m  = rs_m + NM;                    // 10240
    int* es_m  = fc_m + NM;                    // 40960
    int* gs_p  = es_m + EM;                    // 257 (+pad)
    int* gs_m  = gs_p + 260;                   // 257 (+pad)
    int* bsum  = gs_m + 260;                   // 384 (NBP+NBM=340)

    const int BLK = 256;

    // ---- fused CSR build + W pack ----
    hipMemsetAsync(deg_p, 0, (size_t)(NP + NM) * sizeof(int), stream);
    deg2_kernel<<<cdiv(EP + EM, BLK), BLK, 0, stream>>>(pro_ei + EP, deg_p, EP, mol_ei + EM, deg_m, EM);
    degsum2_kernel<<<NBP + NBM, 256, 0, stream>>>(deg_p, NP, NBP, deg_m, NM, bsum);
    scan2_kernel<<<1, 512, 0, stream>>>(bsum, NBP, NBM);
    alloc_scan2_kernel<<<NBP + NBM, 256, 0, stream>>>(deg_p, rs_p, fc_p, norm_p, NP, NBP,
                                                      deg_m, rs_m, fc_m, norm_m, NM, bsum);
    fill2_kernel<<<cdiv(EP + EM, BLK), BLK, 0, stream>>>(pro_ei, pro_ei + EP, fc_p, es_p, EP,
                                                         mol_ei, mol_ei + EM, fc_m, es_m, EM);
    gs2_kernel<<<cdiv(NP + NM, BLK), BLK, 0, stream>>>(pro_batch, gs_p, NP, mol_batch, gs_m, NM, 256);
    pad2_kernel<<<cdiv(NP * 64 + NM * 96, BLK), BLK, 0, stream>>>(pro_x, Rp, NP, 54, 64,
                                                                  mol_x, Rm, NM, 78, 96);
    wpack_kernel<<<cdiv(143360 + 1088, 256), 256, 0, stream>>>(
        pw1, pw2, pw3, pb1, pb2, pb3, mw1, mw2, mw3, mb1, mb2, mb3, WpkH, WpkL, Bpk);

    const int NB_P = NP / 64;   // 1200
    const int NB_M = NM / 64;   // 160

    // L1: R(x0 pad) -> P
    fused_gcn2_kernel<64, 64, 96, 128><<<NB_P + NB_M, 512, 0, stream>>>(
        Rp, norm_p, rs_p, deg_p, es_p, WpkH + 0, WpkL + 0, Bpk + 0, Pp, NB_P,
        Rm, norm_m, rs_m, deg_m, es_m, WpkH + 45056, WpkL + 45056, Bpk + 448, Pm);
    // L2: P -> R
    fused_gcn2_kernel<64, 128, 128, 192><<<NB_P + NB_M, 512, 0, stream>>>(
        Pp, norm_p, rs_p, deg_p, es_p, WpkH + 4096, WpkL + 4096, Bpk + 64, Rp, NB_P,
        Pm, norm_m, rs_m, deg_m, es_m, WpkH + 57344, WpkL + 57344, Bpk + 576, Rm);
    // L3: R -> P
    fused_gcn2_kernel<128, 256, 192, 320><<<NB_P + NB_M, 512, 0, stream>>>(
        Rp, norm_p, rs_p, deg_p, es_p, WpkH + 12288, WpkL + 12288, Bpk + 192, Pp, NB_P,
        Rm, norm_m, rs_m, deg_m, es_m, WpkH + 81920, WpkL + 81920, Bpk + 768, Pm);

    // row-parallel pool (bf16 in, fp32 compact out)
    pool4_kernel<<<512, 1024, 0, stream>>>(Pp, gs_p, pool_p, Pm, gs_m, pool_m);

    // fused branch fc1 (relu, K=216/312, N=1024): MR=4, JT=64; LDS sized for K=312
    {
        int gxA = 1024 / 64, nbA = gxA * (256 / 4);
        int gxB = 1024 / 64, nbB = gxB * (256 / 4);
        size_t lds = (size_t)(4 * 312 + 16 * 4 * 64) * sizeof(float);
        fc2_kernel<true, 4, 64><<<nbA + nbB, 256, lds, stream>>>(
            pool_p, pfw1, pfb1, fcb_p, 216, 1024, 1024, 0, nbA, gxA,
            pool_m, mfw1, mfb1, fcb_m, 312, 1024, 1024, 0, gxB);
    }
    // fused branch fc2 (no relu, K=1024, N=128 -> xc cols): MR=2, JT=32
    {
        int gxA = 128 / 32, nbA = gxA * (256 / 2);
        int gxB = gxA, nbB = nbA;
        size_t lds = (size_t)(2 * 1024 + 32 * 2 * 32) * sizeof(float);
        fc2_kernel<false, 2, 32><<<nbA + nbB, 256, lds, stream>>>(
            fcb_p, pfw2, pfb2, xc, 1024, 128, 256, 128, nbA, gxA,
            fcb_m, mfw2, mfb2, xc, 1024, 128, 256, 0, gxB);
    }

    // combined head
    {
        dim3 grid(1024 / 64, 256 / 4);
        size_t lds = (size_t)(4 * 256 + 16 * 4 * 64) * sizeof(float);
        fc_kernel<true, 4, 64><<<grid, 256, lds, stream>>>(xc, fc1w, fc1b, hb1, 256, 1024, 1024, 0);
    }
    {
        dim3 grid(512 / 64, 256 / 4);
        size_t lds = (size_t)(4 * 1024 + 16 * 4 * 64) * sizeof(float);
        fc_kernel<true, 4, 64><<<grid, 256, lds, stream>>>(hb1, fc2w, fc2b, hb2, 1024, 512, 512, 0);
    }
    matvec_kernel<<<256, 256, 0, stream>>>(hb2, outw, outb, out, 512);
}

// Round 16
// 466.050 us; speedup vs baseline: 1.0516x; 1.0516x over previous
//
#include <hip/hip_runtime.h>

// DGraphDTA r31 = r29 exact (best measured: 459.9us, absmax 2.4e-4).
// r30 post-mortem: 512-thread L3 = 1 piece/thread -> worst straggler tail;
// L3 87->104us despite occ 17.6->32.4%. Wave-count now falsified in BOTH
// byte-bound (r25) and latency-bound (r30) regimes. All structural levers
// (blocks r23, threads r25/r30, pieces r26, scheduling r28) are null or
// negative; wins came only from byte cuts (MFMA r19, fusion r22, bf16 r29)
// and serial-kernel parallelism (pool r20). Locking in the optimum.

static inline int cdiv(int a, int b) { return (a + b - 1) / b; }

// ---------------- bf16 helpers ----------------

__device__ __forceinline__ unsigned short f2bf(float x) {
    unsigned u = __float_as_uint(x);
    u += 0x7FFFu + ((u >> 16) & 1u);   // RNE
    return (unsigned short)(u >> 16);
}
__device__ __forceinline__ float bf2f(unsigned short h) {
    return __uint_as_float((unsigned)h << 16);
}

// ---------------- fused CSR build ----------------

__global__ void deg2_kernel(const int* __restrict__ dstA, int* __restrict__ degA, int EA,
                            const int* __restrict__ dstB, int* __restrict__ degB, int EB) {
    int t = blockIdx.x * blockDim.x + threadIdx.x;
    if (t < EA) { atomicAdd(&degA[dstA[t]], 1); return; }
    t -= EA;
    if (t < EB) atomicAdd(&degB[dstB[t]], 1);
}

__global__ void degsum2_kernel(const int* __restrict__ deg_p, int NP, int nbp,
                               const int* __restrict__ deg_m, int NM, int* __restrict__ bsum) {
    __shared__ int s[256];
    int b = blockIdx.x, tid = threadIdx.x;
    const int* deg; int N, bi;
    if (b < nbp) { deg = deg_p; N = NP; bi = b; }
    else         { deg = deg_m; N = NM; bi = b - nbp; }
    int t = bi * 256 + tid;
    s[tid] = (t < N) ? deg[t] : 0;
    __syncthreads();
    for (int off = 128; off > 0; off >>= 1) {
        if (tid < off) s[tid] += s[tid + off];
        __syncthreads();
    }
    if (tid == 0) bsum[b] = s[0];
}

__global__ void scan2_kernel(int* __restrict__ bsum, int nbp, int nbm) {
    __shared__ int s[512];
    int tid = threadIdx.x;
    int total = nbp + nbm;
    int v = (tid < total) ? bsum[tid] : 0;
    bool isMol = (tid >= nbp);
    s[tid] = v;
    __syncthreads();
    for (int off = 1; off < 512; off <<= 1) {
        int x = 0;
        if (tid >= off) {
            int src = tid - off;
            if ((src >= nbp) == isMol) x = s[src];
        }
        __syncthreads();
        s[tid] += x;
        __syncthreads();
    }
    if (tid < total) bsum[tid] = s[tid] - v;
}

__global__ void alloc_scan2_kernel(const int* __restrict__ deg_p, int* rs_p, int* fc_p, float* n_p,
                                   int NP, int nbp,
                                   const int* __restrict__ deg_m, int* rs_m, int* fc_m, float* n_m,
                                   int NM, const int* __restrict__ bsum) {
    __shared__ int s[256];
    int b = blockIdx.x, tid = threadIdx.x;
    const int* deg; int* rs; int* fc; float* nrm; int N, bi;
    if (b < nbp) { deg = deg_p; rs = rs_p; fc = fc_p; nrm = n_p; N = NP; bi = b; }
    else         { deg = deg_m; rs = rs_m; fc = fc_m; nrm = n_m; N = NM; bi = b - nbp; }
    int t = bi * 256 + tid;
    int v = (t < N) ? deg[t] : 0;
    s[tid] = v;
    __syncthreads();
    for (int off = 1; off < 256; off <<= 1) {
        int x = (tid >= off) ? s[tid - off] : 0;
        __syncthreads();
        s[tid] += x;
        __syncthreads();
    }
    if (t < N) {
        int start = bsum[b] + s[tid] - v;
        rs[t] = start;
        fc[t] = start;
        nrm[t] = rsqrtf((float)v + 1.0f);
    }
}

__global__ void fill2_kernel(const int* srcA, const int* dstA, int* fcA, int* esA, int EA,
                             const int* srcB, const int* dstB, int* fcB, int* esB, int EB) {
    int t = blockIdx.x * blockDim.x + threadIdx.x;
    if (t < EA) { int p = atomicAdd(&fcA[dstA[t]], 1); esA[p] = srcA[t]; return; }
    t -= EA;
    if (t < EB) { int p = atomicAdd(&fcB[dstB[t]], 1); esB[p] = srcB[t]; }
}

__device__ __forceinline__ void gs_body(const int* batch, int* gs, int t, int N, int B) {
    int b = batch[t];
    int bp = (t == 0) ? -1 : batch[t - 1];
    for (int g = bp + 1; g <= b; ++g) gs[g] = t;
    if (t == N - 1) for (int g = b + 1; g <= B; ++g) gs[g] = N;
}

__global__ void gs2_kernel(const int* batchA, int* gsA, int NA,
                           const int* batchB, int* gsB, int NB, int B) {
    int t = blockIdx.x * blockDim.x + threadIdx.x;
    if (t < NA) { gs_body(batchA, gsA, t, NA, B); return; }
    t -= NA;
    if (t < NB) gs_body(batchB, gsB, t, NB, B);
}

// pad + convert x0 to bf16 rows
__global__ void pad2_kernel(const float* xA, unsigned short* yA, int NA, int FA, int SA,
                            const float* xB, unsigned short* yB, int NB, int FB, int SB) {
    int t = blockIdx.x * blockDim.x + threadIdx.x;
    if (t < NA * SA) {
        int r = t / SA, j = t - r * SA;
        yA[t] = (j < FA) ? f2bf(xA[(size_t)r * FA + j]) : (unsigned short)0;
        return;
    }
    t -= NA * SA;
    if (t < NB * SB) {
        int r = t / SB, j = t - r * SB;
        yB[t] = (j < FB) ? f2bf(xB[(size_t)r * FB + j]) : (unsigned short)0;
    }
}

// ---------------- W pack: transpose + pad + bf16 hi/lo split ----------------
//   seg offW    Kp   Np   K   N     offB
//   p1  0       64   64   54  54    0
//   p2  4096    64   128  54  108   64
//   p3  12288   128  256  108 216   192
//   m1  45056   96   128  78  78    448
//   m2  57344   128  192  78  156   576
//   m3  81920   192  320  156 312   768   (totals: 143360 W, 1088 bias)

__global__ void wpack_kernel(
    const float* __restrict__ w1p, const float* __restrict__ w2p, const float* __restrict__ w3p,
    const float* __restrict__ b1p, const float* __restrict__ b2p, const float* __restrict__ b3p,
    const float* __restrict__ w1m, const float* __restrict__ w2m, const float* __restrict__ w3m,
    const float* __restrict__ b1m, const float* __restrict__ b2m, const float* __restrict__ b3m,
    unsigned short* __restrict__ Wh, unsigned short* __restrict__ Wl, float* __restrict__ Bp)
{
    int t = blockIdx.x * 256 + threadIdx.x;
    if (t < 143360) {
        const float* w; int Kp, K, N, off;
        if      (t <  4096) { w = w1p; Kp = 64;  K = 54;  N = 54;  off = 0; }
        else if (t < 12288) { w = w2p; Kp = 64;  K = 54;  N = 108; off = 4096; }
        else if (t < 45056) { w = w3p; Kp = 128; K = 108; N = 216; off = 12288; }
        else if (t < 57344) { w = w1m; Kp = 96;  K = 78;  N = 78;  off = 45056; }
        else if (t < 81920) { w = w2m; Kp = 128; K = 78;  N = 156; off = 57344; }
        else                { w = w3m; Kp = 192; K = 156; N = 312; off = 81920; }
        int local = t - off;
        int n = local / Kp, k = local - n * Kp;
        float v = (k < K && n < N) ? w[(size_t)k * N + n] : 0.0f;
        unsigned short h = f2bf(v);
        Wh[t] = h;
        Wl[t] = f2bf(v - bf2f(h));
        return;
    }
    int u = t - 143360;
    if (u < 1088) {
        const float* b; int N, off;
        if      (u <  64) { b = b1p; N = 54;  off = 0; }
        else if (u < 192) { b = b2p; N = 108; off = 64; }
        else if (u < 448) { b = b3p; N = 216; off = 192; }
        else if (u < 576) { b = b1m; N = 78;  off = 448; }
        else if (u < 768) { b = b2m; N = 156; off = 576; }
        else              { b = b3m; N = 312; off = 768; }
        int n = u - off;
        Bp[u] = (n < N) ? b[n] : 0.0f;
    }
}

// ---------------- fused gather+GEMM (64 rows x full Np, bf16 activations) ----------------

typedef __attribute__((ext_vector_type(8))) short s16x8;
typedef __attribute__((ext_vector_type(4))) float f32x4_t;

template <int KP, int NPo>
__device__ __forceinline__ void fused_body(
    const unsigned short* __restrict__ X, const float* __restrict__ norm,
    const int* __restrict__ rs, const int* __restrict__ deg, const int* __restrict__ es,
    const unsigned short* __restrict__ Wh, const unsigned short* __restrict__ Wl,
    const float* __restrict__ bias, unsigned short* __restrict__ out,
    int brow, unsigned short* Ah, unsigned short* Al)
{
    constexpr int LDK = KP + 8;   // shorts; row offset = 4 banks mod 32 -> <=2-way
    constexpr int UV  = KP / 8;   // ushort8 units per row
    constexpr int UV2 = UV / 2;   // 2-unit pieces per row
    constexpr int NF  = NPo / 64; // N-frags per wave
    const int tid = threadIdx.x;

    // ---- phase 1: aggregate 64 bf16 rows -> fp32 -> bf16 hi/lo in LDS ----
    const s16x8* xv = reinterpret_cast<const s16x8*>(X);
    for (int p = tid; p < 64 * UV2; p += 256) {
        int r = p / UV2, q = p - r * UV2;
        int n = brow + r;
        size_t base = (size_t)n * UV;
        float nn = norm[n];
        s16x8 u0 = xv[base + q], u1 = xv[base + q + UV2];
        float a0[8], a1[8];
#pragma unroll
        for (int k = 0; k < 8; ++k) {
            a0[k] = nn * bf2f((unsigned short)u0[k]);
            a1[k] = nn * bf2f((unsigned short)u1[k]);
        }
        int rsv = rs[n], d = deg[n];
        const int* e = es + rsv;
        int i = 0;
        for (; i + 2 <= d; i += 2) {
            int s0 = e[i], s1 = e[i + 1];
            float n0 = norm[s0], n1 = norm[s1];
            size_t b0 = (size_t)s0 * UV, b1 = (size_t)s1 * UV;
            s16x8 v00 = xv[b0 + q], v01 = xv[b0 + q + UV2];
            s16x8 v10 = xv[b1 + q], v11 = xv[b1 + q + UV2];
#pragma unroll
            for (int k = 0; k < 8; ++k) {
                a0[k] = fmaf(n0, bf2f((unsigned short)v00[k]), a0[k]);
                a1[k] = fmaf(n0, bf2f((unsigned short)v01[k]), a1[k]);
            }
#pragma unroll
            for (int k = 0; k < 8; ++k) {
                a0[k] = fmaf(n1, bf2f((unsigned short)v10[k]), a0[k]);
                a1[k] = fmaf(n1, bf2f((unsigned short)v11[k]), a1[k]);
            }
        }
        if (i < d) {
            int s0 = e[i];
            float n0 = norm[s0];
            size_t b0 = (size_t)s0 * UV;
            s16x8 v00 = xv[b0 + q], v01 = xv[b0 + q + UV2];
#pragma unroll
            for (int k = 0; k < 8; ++k) {
                a0[k] = fmaf(n0, bf2f((unsigned short)v00[k]), a0[k]);
                a1[k] = fmaf(n0, bf2f((unsigned short)v01[k]), a1[k]);
            }
        }
        s16x8 h0, l0, h1, l1;
#pragma unroll
        for (int k = 0; k < 8; ++k) {
            unsigned short h = f2bf(a0[k]);
            h0[k] = (short)h; l0[k] = (short)f2bf(a0[k] - bf2f(h));
            unsigned short g = f2bf(a1[k]);
            h1[k] = (short)g; l1[k] = (short)f2bf(a1[k] - bf2f(g));
        }
        *reinterpret_cast<s16x8*>(&Ah[r * LDK + 8 * q]) = h0;
        *reinterpret_cast<s16x8*>(&Ah[r * LDK + 8 * (q + UV2)]) = h1;
        *reinterpret_cast<s16x8*>(&Al[r * LDK + 8 * q]) = l0;
        *reinterpret_cast<s16x8*>(&Al[r * LDK + 8 * (q + UV2)]) = l1;
    }
    __syncthreads();

    // ---- phase 2: bf16x3 MFMA over all Np columns (W-frags from global/L2) ----
    const int wave = tid >> 6, lane = tid & 63;
    const int l15 = lane & 15, l4 = lane >> 4;
    const int nc0 = wave * (NPo / 4);

    f32x4_t acc[4][NF];
#pragma unroll
    for (int mf = 0; mf < 4; ++mf)
#pragma unroll
        for (int nf = 0; nf < NF; ++nf)
            acc[mf][nf] = (f32x4_t){0.f, 0.f, 0.f, 0.f};

    for (int k0 = 0; k0 < KP; k0 += 32) {
        s16x8 ah[4], al[4];
#pragma unroll
        for (int mf = 0; mf < 4; ++mf) {
            int r = mf * 16 + l15;
            ah[mf] = *reinterpret_cast<const s16x8*>(&Ah[r * LDK + k0 + l4 * 8]);
            al[mf] = *reinterpret_cast<const s16x8*>(&Al[r * LDK + k0 + l4 * 8]);
        }
#pragma unroll
        for (int nf = 0; nf < NF; ++nf) {
            size_t wb = (size_t)(nc0 + nf * 16 + l15) * KP + k0 + l4 * 8;
            s16x8 bh = *reinterpret_cast<const s16x8*>(&Wh[wb]);
            s16x8 bl = *reinterpret_cast<const s16x8*>(&Wl[wb]);
#pragma unroll
            for (int mf = 0; mf < 4; ++mf) {
                acc[mf][nf] = __builtin_amdgcn_mfma_f32_16x16x32_bf16(ah[mf], bh, acc[mf][nf], 0, 0, 0);
                acc[mf][nf] = __builtin_amdgcn_mfma_f32_16x16x32_bf16(ah[mf], bl, acc[mf][nf], 0, 0, 0);
                acc[mf][nf] = __builtin_amdgcn_mfma_f32_16x16x32_bf16(al[mf], bh, acc[mf][nf], 0, 0, 0);
            }
        }
    }

    // epilogue: C frag col = lane&15, row = (lane>>4)*4 + reg; store bf16
#pragma unroll
    for (int mf = 0; mf < 4; ++mf) {
#pragma unroll
        for (int reg = 0; reg < 4; ++reg) {
            int gm = brow + mf * 16 + l4 * 4 + reg;
            float sc = norm[gm];
#pragma unroll
            for (int nf = 0; nf < NF; ++nf) {
                int gn = nc0 + nf * 16 + l15;
                float v = fmaxf(fmaf(sc, acc[mf][nf][reg], bias[gn]), 0.f);
                out[(size_t)gm * NPo + gn] = f2bf(v);
            }
        }
    }
}

template <int KPA, int NPA, int KPB, int NPB>
__global__ __launch_bounds__(256) void fused_gcn2_kernel(
    const unsigned short* XA, const float* nA, const int* rsA, const int* dA, const int* esA,
    const unsigned short* WhA, const unsigned short* WlA, const float* bsA,
    unsigned short* oA, int nbA,
    const unsigned short* XB, const float* nB, const int* rsB, const int* dB, const int* esB,
    const unsigned short* WhB, const unsigned short* WlB, const float* bsB,
    unsigned short* oB)
{
    constexpr int KMAX = (KPA > KPB ? KPA : KPB);
    __shared__ __align__(16) unsigned short Ah[64 * (KMAX + 8)];
    __shared__ __align__(16) unsigned short Al[64 * (KMAX + 8)];
    int bid = blockIdx.x;
    if (bid < nbA)
        fused_body<KPA, NPA>(XA, nA, rsA, dA, esA, WhA, WlA, bsA, oA, bid * 64, Ah, Al);
    else
        fused_body<KPB, NPB>(XB, nB, rsB, dB, esB, WhB, WlB, bsB, oB, (bid - nbA) * 64, Ah, Al);
}

// ---------------- vec helpers (fc path, fp32) ----------------

__device__ __forceinline__ float4 vmad(float s, float4 a, float4 b) {
    return make_float4(fmaf(s, a.x, b.x), fmaf(s, a.y, b.y), fmaf(s, a.z, b.z), fmaf(s, a.w, b.w));
}

// ---------------- FC (M=256): M-reuse + deep split-K ----------------

template <bool RELU, int MR, int JT>
__device__ __forceinline__ void fc_body(
    const float* __restrict__ X, const float* __restrict__ W,
    const float* __restrict__ bias, float* __restrict__ out,
    int K, int N, int out_stride, int out_off, int bx, int by, float* smem)
{
    constexpr int TJ = JT / 4;
    constexpr int SK = 256 / TJ;
    float* Xs = smem;
    float* red = smem + MR * K;

    const int tid = threadIdx.x;
    const int m0 = by * MR;
    const int j0 = bx * JT;

    for (int idx = tid; idx < MR * K; idx += 256) {
        int r = idx / K, k = idx - r * K;
        Xs[idx] = X[(size_t)(m0 + r) * K + k];
    }
    __syncthreads();

    const int tj = tid % TJ;
    const int s  = tid / TJ;
    const int chunk = (K + SK - 1) / SK;
    const int kb = s * chunk;
    const int ke = min(K, kb + chunk);

    const float4* w4 = reinterpret_cast<const float4*>(W + j0) + tj;
    const int wstride = N >> 2;

    float4 acc[MR];
#pragma unroll
    for (int r = 0; r < MR; ++r) acc[r] = make_float4(0.f, 0.f, 0.f, 0.f);
    for (int k = kb; k < ke; ++k) {
        float4 w = w4[(size_t)k * wstride];
#pragma unroll
        for (int r = 0; r < MR; ++r)
            acc[r] = vmad(Xs[r * K + k], w, acc[r]);
    }
#pragma unroll
    for (int r = 0; r < MR; ++r) {
        float* rr = red + ((s * MR + r) * JT) + tj * 4;
        rr[0] = acc[r].x; rr[1] = acc[r].y; rr[2] = acc[r].z; rr[3] = acc[r].w;
    }
    __syncthreads();

    for (int o = tid; o < MR * JT; o += 256) {
        int r = o / JT, j = o - r * JT;
        float v = 0.f;
#pragma unroll
        for (int ss = 0; ss < SK; ++ss) v += red[(ss * MR + r) * JT + j];
        v += bias[j0 + j];
        if (RELU) v = fmaxf(v, 0.0f);
        out[(size_t)(m0 + r) * out_stride + out_off + j0 + j] = v;
    }
}

template <bool RELU, int MR, int JT>
__global__ __launch_bounds__(256) void fc2_kernel(
    const float* XA, const float* WA, const float* bA, float* oA,
    int KA, int NA, int osA, int ooA, int nbA, int gxA,
    const float* XB, const float* WB, const float* bB, float* oB,
    int KB, int NB, int osB, int ooB, int gxB)
{
    extern __shared__ float smem[];
    int bid = blockIdx.x;
    if (bid < nbA) {
        fc_body<RELU, MR, JT>(XA, WA, bA, oA, KA, NA, osA, ooA, bid % gxA, bid / gxA, smem);
    } else {
        bid -= nbA;
        fc_body<RELU, MR, JT>(XB, WB, bB, oB, KB, NB, osB, ooB, bid % gxB, bid / gxB, smem);
    }
}

template <bool RELU, int MR, int JT>
__global__ __launch_bounds__(256) void fc_kernel(
    const float* X, const float* W, const float* b, float* o,
    int K, int N, int out_stride, int out_off)
{
    extern __shared__ float smem[];
    fc_body<RELU, MR, JT>(X, W, b, o, K, N, out_stride, out_off, blockIdx.x, blockIdx.y, smem);
}

// final layer: one block per row, 256 threads, LDS tree reduce (K=512)
__global__ __launch_bounds__(256) void matvec_kernel(
    const float* __restrict__ X, const float* __restrict__ W,
    const float* __restrict__ bias, float* __restrict__ out, int K)
{
    __shared__ float red[256];
    const int m = blockIdx.x;
    const int tid = threadIdx.x;
    float acc = 0.f;
    for (int k = tid; k < K; k += 256) acc = fmaf(X[(size_t)m * K + k], W[k], acc);
    red[tid] = acc;
    __syncthreads();
    for (int w = 128; w >= 64; w >>= 1) {
        if (tid < w) red[tid] += red[tid + w];
        __syncthreads();
    }
    if (tid < 64) {
        float v = red[tid];
        for (int off = 32; off > 0; off >>= 1) v += __shfl_down(v, off, 64);
        if (tid == 0) out[m] = v + bias[0];
    }
}

// ---------------- row-parallel pooling (block per graph, bf16 input) ----------------
// pro: U=27 ushort8 units (216 elems), stride 32 units; mol: U=39, stride 40.

__global__ __launch_bounds__(1024) void pool4_kernel(
    const unsigned short* __restrict__ xA, const int* __restrict__ gsA, float* __restrict__ poolA,
    const unsigned short* __restrict__ xB, const int* __restrict__ gsB, float* __restrict__ poolB)
{
    __shared__ float red[1024 * 8];
    const int b = blockIdx.x, tid = threadIdx.x;
    const s16x8* xv; const int* gs; float* pool; int U, sv, g;
    if (b < 256) { xv = (const s16x8*)xA; gs = gsA; pool = poolA; U = 27; sv = 32; g = b; }
    else         { xv = (const s16x8*)xB; gs = gsB; pool = poolB; U = 39; sv = 40; g = b - 256; }
    const int s = gs[g], c = gs[g + 1] - s;
    const int nrg = 1024 / U;
    const int jv = tid % U, rg = tid / U;

    float a[8] = {0.f, 0.f, 0.f, 0.f, 0.f, 0.f, 0.f, 0.f};
    if (rg < nrg) {
        for (int i = rg; i < c; i += nrg) {
            s16x8 u = xv[(size_t)(s + i) * sv + jv];
#pragma unroll
            for (int k = 0; k < 8; ++k) a[k] += bf2f((unsigned short)u[k]);
        }
    }
#pragma unroll
    for (int k = 0; k < 8; ++k) red[tid * 8 + k] = a[k];
    __syncthreads();
    if (rg == 0) {
        for (int q = 1; q < nrg; ++q) {
            const float* rr = &red[(q * U + jv) * 8];
#pragma unroll
            for (int k = 0; k < 8; ++k) a[k] += rr[k];
        }
        const float fc_ = (float)max(c, 1);
        float* po = &pool[(size_t)g * (U * 8) + jv * 8];
#pragma unroll
        for (int k = 0; k < 8; ++k) po[k] = a[k] / fc_;
    }
}

extern "C" void kernel_launch(void* const* d_in, const int* in_sizes, int n_in,
                              void* d_out, int out_size, void* d_ws, size_t ws_size,
                              hipStream_t stream) {
    const float* mol_x     = (const float*)d_in[0];
    const int*   mol_ei    = (const int*)  d_in[1];
    const int*   mol_batch = (const int*)  d_in[2];
    const float* pro_x     = (const float*)d_in[3];
    const int*   pro_ei    = (const int*)  d_in[4];
    const int*   pro_batch = (const int*)  d_in[5];
    const float* mw1 = (const float*)d_in[6],  * mb1 = (const float*)d_in[7];
    const float* mw2 = (const float*)d_in[8],  * mb2 = (const float*)d_in[9];
    const float* mw3 = (const float*)d_in[10], * mb3 = (const float*)d_in[11];
    const float* mfw1 = (const float*)d_in[12], * mfb1 = (const float*)d_in[13];
    const float* mfw2 = (const float*)d_in[14], * mfb2 = (const float*)d_in[15];
    const float* pw1 = (const float*)d_in[16], * pb1 = (const float*)d_in[17];
    const float* pw2 = (const float*)d_in[18], * pb2 = (const float*)d_in[19];
    const float* pw3 = (const float*)d_in[20], * pb3 = (const float*)d_in[21];
    const float* pfw1 = (const float*)d_in[22], * pfb1 = (const float*)d_in[23];
    const float* pfw2 = (const float*)d_in[24], * pfb2 = (const float*)d_in[25];
    const float* fc1w = (const float*)d_in[26], * fc1b = (const float*)d_in[27];
    const float* fc2w = (const float*)d_in[28], * fc2b = (const float*)d_in[29];
    const float* outw = (const float*)d_in[30], * outb = (const float*)d_in[31];
    float* out = (float*)d_out;

    // ---- dims ----
    const int NP = 76800, EP = 768000;
    const int NM = 10240, EM = 40960;
    const int NBP = cdiv(NP, 256), NBM = cdiv(NM, 256);  // 300, 40
    // padded dims: pro Kp {64,64,128} Np {64,128,256}; mol Kp {96,128,192} Np {128,192,320}

    // ---- workspace layout (bf16 activations) ----
    unsigned short* Pp = (unsigned short*)d_ws;       // 76800*256
    unsigned short* Rp = Pp + (size_t)76800 * 256;    // 76800*128
    unsigned short* Pm = Rp + (size_t)76800 * 128;    // 10240*320
    unsigned short* Rm = Pm + (size_t)10240 * 320;    // 10240*192
    unsigned short* WpkH = Rm + (size_t)10240 * 192;  // 143360
    unsigned short* WpkL = WpkH + 143360;             // 143360
    float* Bpk    = (float*)(WpkL + 143360);          // 1088
    float* norm_p = Bpk + 1088;                       // 76800
    float* norm_m = norm_p + NP;                      // 10240
    float* pool_p = norm_m + NM;                      // 256*216
    float* pool_m = pool_p + 256 * 216;               // 256*312
    float* fcb_p  = pool_m + 256 * 312;               // 256*1024
    float* fcb_m  = fcb_p + 256 * 1024;               // 256*1024
    float* xc     = fcb_m + 256 * 1024;               // 256*256
    float* hb1    = xc + 256 * 256;                   // 256*1024
    float* hb2    = hb1 + 256 * 1024;                 // 256*512
    int* ibase    = (int*)(hb2 + 256 * 512);
    int* deg_p = ibase;                        // 76800 (memset region start)
    int* deg_m = deg_p + NP;                   // 10240
    int* rs_p  = deg_m + NM;                   // 76800
    int* fc_p  = rs_p + NP;                    // 76800
    int* es_p  = fc_p + NP;                    // 768000
    int* rs_m  = es_p + EP;                    // 10240
    int* fc_m  = rs_m + NM;                    // 10240
    int* es_m  = fc_m + NM;                    // 40960
    int* gs_p  = es_m + EM;                    // 257 (+pad)
    int* gs_m  = gs_p + 260;                   // 257 (+pad)
    int* bsum  = gs_m + 260;                   // 384 (NBP+NBM=340)

    const int BLK = 256;

    // ---- fused CSR build + W pack ----
    hipMemsetAsync(deg_p, 0, (size_t)(NP + NM) * sizeof(int), stream);
    deg2_kernel<<<cdiv(EP + EM, BLK), BLK, 0, stream>>>(pro_ei + EP, deg_p, EP, mol_ei + EM, deg_m, EM);
    degsum2_kernel<<<NBP + NBM, 256, 0, stream>>>(deg_p, NP, NBP, deg_m, NM, bsum);
    scan2_kernel<<<1, 512, 0, stream>>>(bsum, NBP, NBM);
    alloc_scan2_kernel<<<NBP + NBM, 256, 0, stream>>>(deg_p, rs_p, fc_p, norm_p, NP, NBP,
                                                      deg_m, rs_m, fc_m, norm_m, NM, bsum);
    fill2_kernel<<<cdiv(EP + EM, BLK), BLK, 0, stream>>>(pro_ei, pro_ei + EP, fc_p, es_p, EP,
                                                         mol_ei, mol_ei + EM, fc_m, es_m, EM);
    gs2_kernel<<<cdiv(NP + NM, BLK), BLK, 0, stream>>>(pro_batch, gs_p, NP, mol_batch, gs_m, NM, 256);
    pad2_kernel<<<cdiv(NP * 64 + NM * 96, BLK), BLK, 0, stream>>>(pro_x, Rp, NP, 54, 64,
                                                                  mol_x, Rm, NM, 78, 96);
    wpack_kernel<<<cdiv(143360 + 1088, 256), 256, 0, stream>>>(
        pw1, pw2, pw3, pb1, pb2, pb3, mw1, mw2, mw3, mb1, mb2, mb3, WpkH, WpkL, Bpk);

    const int NB_P = NP / 64;   // 1200
    const int NB_M = NM / 64;   // 160

    // L1: R(x0 pad) -> P
    fused_gcn2_kernel<64, 64, 96, 128><<<NB_P + NB_M, 256, 0, stream>>>(
        Rp, norm_p, rs_p, deg_p, es_p, WpkH + 0, WpkL + 0, Bpk + 0, Pp, NB_P,
        Rm, norm_m, rs_m, deg_m, es_m, WpkH + 45056, WpkL + 45056, Bpk + 448, Pm);
    // L2: P -> R
    fused_gcn2_kernel<64, 128, 128, 192><<<NB_P + NB_M, 256, 0, stream>>>(
        Pp, norm_p, rs_p, deg_p, es_p, WpkH + 4096, WpkL + 4096, Bpk + 64, Rp, NB_P,
        Pm, norm_m, rs_m, deg_m, es_m, WpkH + 57344, WpkL + 57344, Bpk + 576, Rm);
    // L3: R -> P
    fused_gcn2_kernel<128, 256, 192, 320><<<NB_P + NB_M, 256, 0, stream>>>(
        Rp, norm_p, rs_p, deg_p, es_p, WpkH + 12288, WpkL + 12288, Bpk + 192, Pp, NB_P,
        Rm, norm_m, rs_m, deg_m, es_m, WpkH + 81920, WpkL + 81920, Bpk + 768, Pm);

    // row-parallel pool (bf16 in, fp32 compact out)
    pool4_kernel<<<512, 1024, 0, stream>>>(Pp, gs_p, pool_p, Pm, gs_m, pool_m);

    // fused branch fc1 (relu, K=216/312, N=1024): MR=4, JT=64; LDS sized for K=312
    {
        int gxA = 1024 / 64, nbA = gxA * (256 / 4);
        int gxB = 1024 / 64, nbB = gxB * (256 / 4);
        size_t lds = (size_t)(4 * 312 + 16 * 4 * 64) * sizeof(float);
        fc2_kernel<true, 4, 64><<<nbA + nbB, 256, lds, stream>>>(
            pool_p, pfw1, pfb1, fcb_p, 216, 1024, 1024, 0, nbA, gxA,
            pool_m, mfw1, mfb1, fcb_m, 312, 1024, 1024, 0, gxB);
    }
    // fused branch fc2 (no relu, K=1024, N=128 -> xc cols): MR=2, JT=32
    {
        int gxA = 128 / 32, nbA = gxA * (256 / 2);
        int gxB = gxA, nbB = nbA;
        size_t lds = (size_t)(2 * 1024 + 32 * 2 * 32) * sizeof(float);
        fc2_kernel<false, 2, 32><<<nbA + nbB, 256, lds, stream>>>(
            fcb_p, pfw2, pfb2, xc, 1024, 128, 256, 128, nbA, gxA,
            fcb_m, mfw2, mfb2, xc, 1024, 128, 256, 0, gxB);
    }

    // combined head
    {
        dim3 grid(1024 / 64, 256 / 4);
        size_t lds = (size_t)(4 * 256 + 16 * 4 * 64) * sizeof(float);
        fc_kernel<true, 4, 64><<<grid, 256, lds, stream>>>(xc, fc1w, fc1b, hb1, 256, 1024, 1024, 0);
    }
    {
        dim3 grid(512 / 64, 256 / 4);
        size_t lds = (size_t)(4 * 1024 + 16 * 4 * 64) * sizeof(float);
        fc_kernel<true, 4, 64><<<grid, 256, lds, stream>>>(hb1, fc2w, fc2b, hb2, 1024, 512, 512, 0);
    }
    matvec_kernel<<<256, 256, 0, stream>>>(hb2, outw, outb, out, 512);
}

// Round 17
// 451.444 us; speedup vs baseline: 1.0856x; 1.0324x over previous
//
#include <hip/hip_runtime.h>

// DGraphDTA r32 = r31/r29 with single-buffer A (drop Al): A = bf16(aggregate),
// C = A*(Whi+Wlo), 2 MFMA terms. Since activations are ALREADY bf16-stored,
// dropping the aggregate's lo-term adds only one more ~2^-9 rounding
// (absmax 2.4e-4 -> ~4-5e-4 expected). LDS halves: L3 51.2->25.6KB ->
// 6 blocks/CU (L2/L1 -> 8, wave-capped); same 256 thr / piece structure
// (r30's straggler failure avoided). Latency-regime wave scaling:
// fused 1.76 TB/s @ 5.6 waves/CU vs standalone 3.9 @ 20 -> expect ~2x BW.

static inline int cdiv(int a, int b) { return (a + b - 1) / b; }

// ---------------- bf16 helpers ----------------

__device__ __forceinline__ unsigned short f2bf(float x) {
    unsigned u = __float_as_uint(x);
    u += 0x7FFFu + ((u >> 16) & 1u);   // RNE
    return (unsigned short)(u >> 16);
}
__device__ __forceinline__ float bf2f(unsigned short h) {
    return __uint_as_float((unsigned)h << 16);
}

// ---------------- fused CSR build ----------------

__global__ void deg2_kernel(const int* __restrict__ dstA, int* __restrict__ degA, int EA,
                            const int* __restrict__ dstB, int* __restrict__ degB, int EB) {
    int t = blockIdx.x * blockDim.x + threadIdx.x;
    if (t < EA) { atomicAdd(&degA[dstA[t]], 1); return; }
    t -= EA;
    if (t < EB) atomicAdd(&degB[dstB[t]], 1);
}

__global__ void degsum2_kernel(const int* __restrict__ deg_p, int NP, int nbp,
                               const int* __restrict__ deg_m, int NM, int* __restrict__ bsum) {
    __shared__ int s[256];
    int b = blockIdx.x, tid = threadIdx.x;
    const int* deg; int N, bi;
    if (b < nbp) { deg = deg_p; N = NP; bi = b; }
    else         { deg = deg_m; N = NM; bi = b - nbp; }
    int t = bi * 256 + tid;
    s[tid] = (t < N) ? deg[t] : 0;
    __syncthreads();
    for (int off = 128; off > 0; off >>= 1) {
        if (tid < off) s[tid] += s[tid + off];
        __syncthreads();
    }
    if (tid == 0) bsum[b] = s[0];
}

__global__ void scan2_kernel(int* __restrict__ bsum, int nbp, int nbm) {
    __shared__ int s[512];
    int tid = threadIdx.x;
    int total = nbp + nbm;
    int v = (tid < total) ? bsum[tid] : 0;
    bool isMol = (tid >= nbp);
    s[tid] = v;
    __syncthreads();
    for (int off = 1; off < 512; off <<= 1) {
        int x = 0;
        if (tid >= off) {
            int src = tid - off;
            if ((src >= nbp) == isMol) x = s[src];
        }
        __syncthreads();
        s[tid] += x;
        __syncthreads();
    }
    if (tid < total) bsum[tid] = s[tid] - v;
}

__global__ void alloc_scan2_kernel(const int* __restrict__ deg_p, int* rs_p, int* fc_p, float* n_p,
                                   int NP, int nbp,
                                   const int* __restrict__ deg_m, int* rs_m, int* fc_m, float* n_m,
                                   int NM, const int* __restrict__ bsum) {
    __shared__ int s[256];
    int b = blockIdx.x, tid = threadIdx.x;
    const int* deg; int* rs; int* fc; float* nrm; int N, bi;
    if (b < nbp) { deg = deg_p; rs = rs_p; fc = fc_p; nrm = n_p; N = NP; bi = b; }
    else         { deg = deg_m; rs = rs_m; fc = fc_m; nrm = n_m; N = NM; bi = b - nbp; }
    int t = bi * 256 + tid;
    int v = (t < N) ? deg[t] : 0;
    s[tid] = v;
    __syncthreads();
    for (int off = 1; off < 256; off <<= 1) {
        int x = (tid >= off) ? s[tid - off] : 0;
        __syncthreads();
        s[tid] += x;
        __syncthreads();
    }
    if (t < N) {
        int start = bsum[b] + s[tid] - v;
        rs[t] = start;
        fc[t] = start;
        nrm[t] = rsqrtf((float)v + 1.0f);
    }
}

__global__ void fill2_kernel(const int* srcA, const int* dstA, int* fcA, int* esA, int EA,
                             const int* srcB, const int* dstB, int* fcB, int* esB, int EB) {
    int t = blockIdx.x * blockDim.x + threadIdx.x;
    if (t < EA) { int p = atomicAdd(&fcA[dstA[t]], 1); esA[p] = srcA[t]; return; }
    t -= EA;
    if (t < EB) { int p = atomicAdd(&fcB[dstB[t]], 1); esB[p] = srcB[t]; }
}

__device__ __forceinline__ void gs_body(const int* batch, int* gs, int t, int N, int B) {
    int b = batch[t];
    int bp = (t == 0) ? -1 : batch[t - 1];
    for (int g = bp + 1; g <= b; ++g) gs[g] = t;
    if (t == N - 1) for (int g = b + 1; g <= B; ++g) gs[g] = N;
}

__global__ void gs2_kernel(const int* batchA, int* gsA, int NA,
                           const int* batchB, int* gsB, int NB, int B) {
    int t = blockIdx.x * blockDim.x + threadIdx.x;
    if (t < NA) { gs_body(batchA, gsA, t, NA, B); return; }
    t -= NA;
    if (t < NB) gs_body(batchB, gsB, t, NB, B);
}

// pad + convert x0 to bf16 rows
__global__ void pad2_kernel(const float* xA, unsigned short* yA, int NA, int FA, int SA,
                            const float* xB, unsigned short* yB, int NB, int FB, int SB) {
    int t = blockIdx.x * blockDim.x + threadIdx.x;
    if (t < NA * SA) {
        int r = t / SA, j = t - r * SA;
        yA[t] = (j < FA) ? f2bf(xA[(size_t)r * FA + j]) : (unsigned short)0;
        return;
    }
    t -= NA * SA;
    if (t < NB * SB) {
        int r = t / SB, j = t - r * SB;
        yB[t] = (j < FB) ? f2bf(xB[(size_t)r * FB + j]) : (unsigned short)0;
    }
}

// ---------------- W pack: transpose + pad + bf16 hi/lo split ----------------
//   seg offW    Kp   Np   K   N     offB
//   p1  0       64   64   54  54    0
//   p2  4096    64   128  54  108   64
//   p3  12288   128  256  108 216   192
//   m1  45056   96   128  78  78    448
//   m2  57344   128  192  78  156   576
//   m3  81920   192  320  156 312   768   (totals: 143360 W, 1088 bias)

__global__ void wpack_kernel(
    const float* __restrict__ w1p, const float* __restrict__ w2p, const float* __restrict__ w3p,
    const float* __restrict__ b1p, const float* __restrict__ b2p, const float* __restrict__ b3p,
    const float* __restrict__ w1m, const float* __restrict__ w2m, const float* __restrict__ w3m,
    const float* __restrict__ b1m, const float* __restrict__ b2m, const float* __restrict__ b3m,
    unsigned short* __restrict__ Wh, unsigned short* __restrict__ Wl, float* __restrict__ Bp)
{
    int t = blockIdx.x * 256 + threadIdx.x;
    if (t < 143360) {
        const float* w; int Kp, K, N, off;
        if      (t <  4096) { w = w1p; Kp = 64;  K = 54;  N = 54;  off = 0; }
        else if (t < 12288) { w = w2p; Kp = 64;  K = 54;  N = 108; off = 4096; }
        else if (t < 45056) { w = w3p; Kp = 128; K = 108; N = 216; off = 12288; }
        else if (t < 57344) { w = w1m; Kp = 96;  K = 78;  N = 78;  off = 45056; }
        else if (t < 81920) { w = w2m; Kp = 128; K = 78;  N = 156; off = 57344; }
        else                { w = w3m; Kp = 192; K = 156; N = 312; off = 81920; }
        int local = t - off;
        int n = local / Kp, k = local - n * Kp;
        float v = (k < K && n < N) ? w[(size_t)k * N + n] : 0.0f;
        unsigned short h = f2bf(v);
        Wh[t] = h;
        Wl[t] = f2bf(v - bf2f(h));
        return;
    }
    int u = t - 143360;
    if (u < 1088) {
        const float* b; int N, off;
        if      (u <  64) { b = b1p; N = 54;  off = 0; }
        else if (u < 192) { b = b2p; N = 108; off = 64; }
        else if (u < 448) { b = b3p; N = 216; off = 192; }
        else if (u < 576) { b = b1m; N = 78;  off = 448; }
        else if (u < 768) { b = b2m; N = 156; off = 576; }
        else              { b = b3m; N = 312; off = 768; }
        int n = u - off;
        Bp[u] = (n < N) ? b[n] : 0.0f;
    }
}

// ---------------- fused gather+GEMM (64 rows x full Np, bf16 A single-buffer) ----------------

typedef __attribute__((ext_vector_type(8))) short s16x8;
typedef __attribute__((ext_vector_type(4))) float f32x4_t;

template <int KP, int NPo>
__device__ __forceinline__ void fused_body(
    const unsigned short* __restrict__ X, const float* __restrict__ norm,
    const int* __restrict__ rs, const int* __restrict__ deg, const int* __restrict__ es,
    const unsigned short* __restrict__ Wh, const unsigned short* __restrict__ Wl,
    const float* __restrict__ bias, unsigned short* __restrict__ out,
    int brow, unsigned short* Ah)
{
    constexpr int LDK = KP + 8;   // shorts; row offset = 4 banks mod 32 -> <=2-way
    constexpr int UV  = KP / 8;   // ushort8 units per row
    constexpr int UV2 = UV / 2;   // 2-unit pieces per row
    constexpr int NF  = NPo / 64; // N-frags per wave
    const int tid = threadIdx.x;

    // ---- phase 1: aggregate 64 bf16 rows -> fp32 -> bf16 in LDS ----
    const s16x8* xv = reinterpret_cast<const s16x8*>(X);
    for (int p = tid; p < 64 * UV2; p += 256) {
        int r = p / UV2, q = p - r * UV2;
        int n = brow + r;
        size_t base = (size_t)n * UV;
        float nn = norm[n];
        s16x8 u0 = xv[base + q], u1 = xv[base + q + UV2];
        float a0[8], a1[8];
#pragma unroll
        for (int k = 0; k < 8; ++k) {
            a0[k] = nn * bf2f((unsigned short)u0[k]);
            a1[k] = nn * bf2f((unsigned short)u1[k]);
        }
        int rsv = rs[n], d = deg[n];
        const int* e = es + rsv;
        int i = 0;
        for (; i + 2 <= d; i += 2) {
            int s0 = e[i], s1 = e[i + 1];
            float n0 = norm[s0], n1 = norm[s1];
            size_t b0 = (size_t)s0 * UV, b1 = (size_t)s1 * UV;
            s16x8 v00 = xv[b0 + q], v01 = xv[b0 + q + UV2];
            s16x8 v10 = xv[b1 + q], v11 = xv[b1 + q + UV2];
#pragma unroll
            for (int k = 0; k < 8; ++k) {
                a0[k] = fmaf(n0, bf2f((unsigned short)v00[k]), a0[k]);
                a1[k] = fmaf(n0, bf2f((unsigned short)v01[k]), a1[k]);
            }
#pragma unroll
            for (int k = 0; k < 8; ++k) {
                a0[k] = fmaf(n1, bf2f((unsigned short)v10[k]), a0[k]);
                a1[k] = fmaf(n1, bf2f((unsigned short)v11[k]), a1[k]);
            }
        }
        if (i < d) {
            int s0 = e[i];
            float n0 = norm[s0];
            size_t b0 = (size_t)s0 * UV;
            s16x8 v00 = xv[b0 + q], v01 = xv[b0 + q + UV2];
#pragma unroll
            for (int k = 0; k < 8; ++k) {
                a0[k] = fmaf(n0, bf2f((unsigned short)v00[k]), a0[k]);
                a1[k] = fmaf(n0, bf2f((unsigned short)v01[k]), a1[k]);
            }
        }
        s16x8 h0, h1;
#pragma unroll
        for (int k = 0; k < 8; ++k) {
            h0[k] = (short)f2bf(a0[k]);
            h1[k] = (short)f2bf(a1[k]);
        }
        *reinterpret_cast<s16x8*>(&Ah[r * LDK + 8 * q]) = h0;
        *reinterpret_cast<s16x8*>(&Ah[r * LDK + 8 * (q + UV2)]) = h1;
    }
    __syncthreads();

    // ---- phase 2: 2-term MFMA (A = bf16 agg; W = hi+lo) over all Np columns ----
    const int wave = tid >> 6, lane = tid & 63;
    const int l15 = lane & 15, l4 = lane >> 4;
    const int nc0 = wave * (NPo / 4);

    f32x4_t acc[4][NF];
#pragma unroll
    for (int mf = 0; mf < 4; ++mf)
#pragma unroll
        for (int nf = 0; nf < NF; ++nf)
            acc[mf][nf] = (f32x4_t){0.f, 0.f, 0.f, 0.f};

    for (int k0 = 0; k0 < KP; k0 += 32) {
        s16x8 ah[4];
#pragma unroll
        for (int mf = 0; mf < 4; ++mf) {
            int r = mf * 16 + l15;
            ah[mf] = *reinterpret_cast<const s16x8*>(&Ah[r * LDK + k0 + l4 * 8]);
        }
#pragma unroll
        for (int nf = 0; nf < NF; ++nf) {
            size_t wb = (size_t)(nc0 + nf * 16 + l15) * KP + k0 + l4 * 8;
            s16x8 bh = *reinterpret_cast<const s16x8*>(&Wh[wb]);
            s16x8 bl = *reinterpret_cast<const s16x8*>(&Wl[wb]);
#pragma unroll
            for (int mf = 0; mf < 4; ++mf) {
                acc[mf][nf] = __builtin_amdgcn_mfma_f32_16x16x32_bf16(ah[mf], bh, acc[mf][nf], 0, 0, 0);
                acc[mf][nf] = __builtin_amdgcn_mfma_f32_16x16x32_bf16(ah[mf], bl, acc[mf][nf], 0, 0, 0);
            }
        }
    }

    // epilogue: C frag col = lane&15, row = (lane>>4)*4 + reg; store bf16
#pragma unroll
    for (int mf = 0; mf < 4; ++mf) {
#pragma unroll
        for (int reg = 0; reg < 4; ++reg) {
            int gm = brow + mf * 16 + l4 * 4 + reg;
            float sc = norm[gm];
#pragma unroll
            for (int nf = 0; nf < NF; ++nf) {
                int gn = nc0 + nf * 16 + l15;
                float v = fmaxf(fmaf(sc, acc[mf][nf][reg], bias[gn]), 0.f);
                out[(size_t)gm * NPo + gn] = f2bf(v);
            }
        }
    }
}

template <int KPA, int NPA, int KPB, int NPB>
__global__ __launch_bounds__(256) void fused_gcn2_kernel(
    const unsigned short* XA, const float* nA, const int* rsA, const int* dA, const int* esA,
    const unsigned short* WhA, const unsigned short* WlA, const float* bsA,
    unsigned short* oA, int nbA,
    const unsigned short* XB, const float* nB, const int* rsB, const int* dB, const int* esB,
    const unsigned short* WhB, const unsigned short* WlB, const float* bsB,
    unsigned short* oB)
{
    constexpr int KMAX = (KPA > KPB ? KPA : KPB);
    __shared__ __align__(16) unsigned short Ah[64 * (KMAX + 8)];
    int bid = blockIdx.x;
    if (bid < nbA)
        fused_body<KPA, NPA>(XA, nA, rsA, dA, esA, WhA, WlA, bsA, oA, bid * 64, Ah);
    else
        fused_body<KPB, NPB>(XB, nB, rsB, dB, esB, WhB, WlB, bsB, oB, (bid - nbA) * 64, Ah);
}

// ---------------- vec helpers (fc path, fp32) ----------------

__device__ __forceinline__ float4 vmad(float s, float4 a, float4 b) {
    return make_float4(fmaf(s, a.x, b.x), fmaf(s, a.y, b.y), fmaf(s, a.z, b.z), fmaf(s, a.w, b.w));
}

// ---------------- FC (M=256): M-reuse + deep split-K ----------------

template <bool RELU, int MR, int JT>
__device__ __forceinline__ void fc_body(
    const float* __restrict__ X, const float* __restrict__ W,
    const float* __restrict__ bias, float* __restrict__ out,
    int K, int N, int out_stride, int out_off, int bx, int by, float* smem)
{
    constexpr int TJ = JT / 4;
    constexpr int SK = 256 / TJ;
    float* Xs = smem;
    float* red = smem + MR * K;

    const int tid = threadIdx.x;
    const int m0 = by * MR;
    const int j0 = bx * JT;

    for (int idx = tid; idx < MR * K; idx += 256) {
        int r = idx / K, k = idx - r * K;
        Xs[idx] = X[(size_t)(m0 + r) * K + k];
    }
    __syncthreads();

    const int tj = tid % TJ;
    const int s  = tid / TJ;
    const int chunk = (K + SK - 1) / SK;
    const int kb = s * chunk;
    const int ke = min(K, kb + chunk);

    const float4* w4 = reinterpret_cast<const float4*>(W + j0) + tj;
    const int wstride = N >> 2;

    float4 acc[MR];
#pragma unroll
    for (int r = 0; r < MR; ++r) acc[r] = make_float4(0.f, 0.f, 0.f, 0.f);
    for (int k = kb; k < ke; ++k) {
        float4 w = w4[(size_t)k * wstride];
#pragma unroll
        for (int r = 0; r < MR; ++r)
            acc[r] = vmad(Xs[r * K + k], w, acc[r]);
    }
#pragma unroll
    for (int r = 0; r < MR; ++r) {
        float* rr = red + ((s * MR + r) * JT) + tj * 4;
        rr[0] = acc[r].x; rr[1] = acc[r].y; rr[2] = acc[r].z; rr[3] = acc[r].w;
    }
    __syncthreads();

    for (int o = tid; o < MR * JT; o += 256) {
        int r = o / JT, j = o - r * JT;
        float v = 0.f;
#pragma unroll
        for (int ss = 0; ss < SK; ++ss) v += red[(ss * MR + r) * JT + j];
        v += bias[j0 + j];
        if (RELU) v = fmaxf(v, 0.0f);
        out[(size_t)(m0 + r) * out_stride + out_off + j0 + j] = v;
    }
}

template <bool RELU, int MR, int JT>
__global__ __launch_bounds__(256) void fc2_kernel(
    const float* XA, const float* WA, const float* bA, float* oA,
    int KA, int NA, int osA, int ooA, int nbA, int gxA,
    const float* XB, const float* WB, const float* bB, float* oB,
    int KB, int NB, int osB, int ooB, int gxB)
{
    extern __shared__ float smem[];
    int bid = blockIdx.x;
    if (bid < nbA) {
        fc_body<RELU, MR, JT>(XA, WA, bA, oA, KA, NA, osA, ooA, bid % gxA, bid / gxA, smem);
    } else {
        bid -= nbA;
        fc_body<RELU, MR, JT>(XB, WB, bB, oB, KB, NB, osB, ooB, bid % gxB, bid / gxB, smem);
    }
}

template <bool RELU, int MR, int JT>
__global__ __launch_bounds__(256) void fc_kernel(
    const float* X, const float* W, const float* b, float* o,
    int K, int N, int out_stride, int out_off)
{
    extern __shared__ float smem[];
    fc_body<RELU, MR, JT>(X, W, b, o, K, N, out_stride, out_off, blockIdx.x, blockIdx.y, smem);
}

// final layer: one block per row, 256 threads, LDS tree reduce (K=512)
__global__ __launch_bounds__(256) void matvec_kernel(
    const float* __restrict__ X, const float* __restrict__ W,
    const float* __restrict__ bias, float* __restrict__ out, int K)
{
    __shared__ float red[256];
    const int m = blockIdx.x;
    const int tid = threadIdx.x;
    float acc = 0.f;
    for (int k = tid; k < K; k += 256) acc = fmaf(X[(size_t)m * K + k], W[k], acc);
    red[tid] = acc;
    __syncthreads();
    for (int w = 128; w >= 64; w >>= 1) {
        if (tid < w) red[tid] += red[tid + w];
        __syncthreads();
    }
    if (tid < 64) {
        float v = red[tid];
        for (int off = 32; off > 0; off >>= 1) v += __shfl_down(v, off, 64);
        if (tid == 0) out[m] = v + bias[0];
    }
}

// ---------------- row-parallel pooling (block per graph, bf16 input) ----------------
// pro: U=27 ushort8 units (216 elems), stride 32 units; mol: U=39, stride 40.

__global__ __launch_bounds__(1024) void pool4_kernel(
    const unsigned short* __restrict__ xA, const int* __restrict__ gsA, float* __restrict__ poolA,
    const unsigned short* __restrict__ xB, const int* __restrict__ gsB, float* __restrict__ poolB)
{
    __shared__ float red[1024 * 8];
    const int b = blockIdx.x, tid = threadIdx.x;
    const s16x8* xv; const int* gs; float* pool; int U, sv, g;
    if (b < 256) { xv = (const s16x8*)xA; gs = gsA; pool = poolA; U = 27; sv = 32; g = b; }
    else         { xv = (const s16x8*)xB; gs = gsB; pool = poolB; U = 39; sv = 40; g = b - 256; }
    const int s = gs[g], c = gs[g + 1] - s;
    const int nrg = 1024 / U;
    const int jv = tid % U, rg = tid / U;

    float a[8] = {0.f, 0.f, 0.f, 0.f, 0.f, 0.f, 0.f, 0.f};
    if (rg < nrg) {
        for (int i = rg; i < c; i += nrg) {
            s16x8 u = xv[(size_t)(s + i) * sv + jv];
#pragma unroll
            for (int k = 0; k < 8; ++k) a[k] += bf2f((unsigned short)u[k]);
        }
    }
#pragma unroll
    for (int k = 0; k < 8; ++k) red[tid * 8 + k] = a[k];
    __syncthreads();
    if (rg == 0) {
        for (int q = 1; q < nrg; ++q) {
            const float* rr = &red[(q * U + jv) * 8];
#pragma unroll
            for (int k = 0; k < 8; ++k) a[k] += rr[k];
        }
        const float fc_ = (float)max(c, 1);
        float* po = &pool[(size_t)g * (U * 8) + jv * 8];
#pragma unroll
        for (int k = 0; k < 8; ++k) po[k] = a[k] / fc_;
    }
}

extern "C" void kernel_launch(void* const* d_in, const int* in_sizes, int n_in,
                              void* d_out, int out_size, void* d_ws, size_t ws_size,
                              hipStream_t stream) {
    const float* mol_x     = (const float*)d_in[0];
    const int*   mol_ei    = (const int*)  d_in[1];
    const int*   mol_batch = (const int*)  d_in[2];
    const float* pro_x     = (const float*)d_in[3];
    const int*   pro_ei    = (const int*)  d_in[4];
    const int*   pro_batch = (const int*)  d_in[5];
    const float* mw1 = (const float*)d_in[6],  * mb1 = (const float*)d_in[7];
    const float* mw2 = (const float*)d_in[8],  * mb2 = (const float*)d_in[9];
    const float* mw3 = (const float*)d_in[10], * mb3 = (const float*)d_in[11];
    const float* mfw1 = (const float*)d_in[12], * mfb1 = (const float*)d_in[13];
    const float* mfw2 = (const float*)d_in[14], * mfb2 = (const float*)d_in[15];
    const float* pw1 = (const float*)d_in[16], * pb1 = (const float*)d_in[17];
    const float* pw2 = (const float*)d_in[18], * pb2 = (const float*)d_in[19];
    const float* pw3 = (const float*)d_in[20], * pb3 = (const float*)d_in[21];
    const float* pfw1 = (const float*)d_in[22], * pfb1 = (const float*)d_in[23];
    const float* pfw2 = (const float*)d_in[24], * pfb2 = (const float*)d_in[25];
    const float* fc1w = (const float*)d_in[26], * fc1b = (const float*)d_in[27];
    const float* fc2w = (const float*)d_in[28], * fc2b = (const float*)d_in[29];
    const float* outw = (const float*)d_in[30], * outb = (const float*)d_in[31];
    float* out = (float*)d_out;

    // ---- dims ----
    const int NP = 76800, EP = 768000;
    const int NM = 10240, EM = 40960;
    const int NBP = cdiv(NP, 256), NBM = cdiv(NM, 256);  // 300, 40
    // padded dims: pro Kp {64,64,128} Np {64,128,256}; mol Kp {96,128,192} Np {128,192,320}

    // ---- workspace layout (bf16 activations) ----
    unsigned short* Pp = (unsigned short*)d_ws;       // 76800*256
    unsigned short* Rp = Pp + (size_t)76800 * 256;    // 76800*128
    unsigned short* Pm = Rp + (size_t)76800 * 128;    // 10240*320
    unsigned short* Rm = Pm + (size_t)10240 * 320;    // 10240*192
    unsigned short* WpkH = Rm + (size_t)10240 * 192;  // 143360
    unsigned short* WpkL = WpkH + 143360;             // 143360
    float* Bpk    = (float*)(WpkL + 143360);          // 1088
    float* norm_p = Bpk + 1088;                       // 76800
    float* norm_m = norm_p + NP;                      // 10240
    float* pool_p = norm_m + NM;                      // 256*216
    float* pool_m = pool_p + 256 * 216;               // 256*312
    float* fcb_p  = pool_m + 256 * 312;               // 256*1024
    float* fcb_m  = fcb_p + 256 * 1024;               // 256*1024
    float* xc     = fcb_m + 256 * 1024;               // 256*256
    float* hb1    = xc + 256 * 256;                   // 256*1024
    float* hb2    = hb1 + 256 * 1024;                 // 256*512
    int* ibase    = (int*)(hb2 + 256 * 512);
    int* deg_p = ibase;                        // 76800 (memset region start)
    int* deg_m = deg_p + NP;                   // 10240
    int* rs_p  = deg_m + NM;                   // 76800
    int* fc_p  = rs_p + NP;                    // 76800
    int* es_p  = fc_p + NP;                    // 768000
    int* rs_m  = es_p + EP;                    // 10240
    int* fc_m  = rs_m + NM;                    // 10240
    int* es_m  = fc_m + NM;                    // 40960
    int* gs_p  = es_m + EM;                    // 257 (+pad)
    int* gs_m  = gs_p + 260;                   // 257 (+pad)
    int* bsum  = gs_m + 260;                   // 384 (NBP+NBM=340)

    const int BLK = 256;

    // ---- fused CSR build + W pack ----
    hipMemsetAsync(deg_p, 0, (size_t)(NP + NM) * sizeof(int), stream);
    deg2_kernel<<<cdiv(EP + EM, BLK), BLK, 0, stream>>>(pro_ei + EP, deg_p, EP, mol_ei + EM, deg_m, EM);
    degsum2_kernel<<<NBP + NBM, 256, 0, stream>>>(deg_p, NP, NBP, deg_m, NM, bsum);
    scan2_kernel<<<1, 512, 0, stream>>>(bsum, NBP, NBM);
    alloc_scan2_kernel<<<NBP + NBM, 256, 0, stream>>>(deg_p, rs_p, fc_p, norm_p, NP, NBP,
                                                      deg_m, rs_m, fc_m, norm_m, NM, bsum);
    fill2_kernel<<<cdiv(EP + EM, BLK), BLK, 0, stream>>>(pro_ei, pro_ei + EP, fc_p, es_p, EP,
                                                         mol_ei, mol_ei + EM, fc_m, es_m, EM);
    gs2_kernel<<<cdiv(NP + NM, BLK), BLK, 0, stream>>>(pro_batch, gs_p, NP, mol_batch, gs_m, NM, 256);
    pad2_kernel<<<cdiv(NP * 64 + NM * 96, BLK), BLK, 0, stream>>>(pro_x, Rp, NP, 54, 64,
                                                                  mol_x, Rm, NM, 78, 96);
    wpack_kernel<<<cdiv(143360 + 1088, 256), 256, 0, stream>>>(
        pw1, pw2, pw3, pb1, pb2, pb3, mw1, mw2, mw3, mb1, mb2, mb3, WpkH, WpkL, Bpk);

    const int NB_P = NP / 64;   // 1200
    const int NB_M = NM / 64;   // 160

    // L1: R(x0 pad) -> P
    fused_gcn2_kernel<64, 64, 96, 128><<<NB_P + NB_M, 256, 0, stream>>>(
        Rp, norm_p, rs_p, deg_p, es_p, WpkH + 0, WpkL + 0, Bpk + 0, Pp, NB_P,
        Rm, norm_m, rs_m, deg_m, es_m, WpkH + 45056, WpkL + 45056, Bpk + 448, Pm);
    // L2: P -> R
    fused_gcn2_kernel<64, 128, 128, 192><<<NB_P + NB_M, 256, 0, stream>>>(
        Pp, norm_p, rs_p, deg_p, es_p, WpkH + 4096, WpkL + 4096, Bpk + 64, Rp, NB_P,
        Pm, norm_m, rs_m, deg_m, es_m, WpkH + 57344, WpkL + 57344, Bpk + 576, Rm);
    // L3: R -> P
    fused_gcn2_kernel<128, 256, 192, 320><<<NB_P + NB_M, 256, 0, stream>>>(
        Rp, norm_p, rs_p, deg_p, es_p, WpkH + 12288, WpkL + 12288, Bpk + 192, Pp, NB_P,
        Rm, norm_m, rs_m, deg_m, es_m, WpkH + 81920, WpkL + 81920, Bpk + 768, Pm);

    // row-parallel pool (bf16 in, fp32 compact out)
    pool4_kernel<<<512, 1024, 0, stream>>>(Pp, gs_p, pool_p, Pm, gs_m, pool_m);

    // fused branch fc1 (relu, K=216/312, N=1024): MR=4, JT=64; LDS sized for K=312
    {
        int gxA = 1024 / 64, nbA = gxA * (256 / 4);
        int gxB = 1024 / 64, nbB = gxB * (256 / 4);
        size_t lds = (size_t)(4 * 312 + 16 * 4 * 64) * sizeof(float);
        fc2_kernel<true, 4, 64><<<nbA + nbB, 256, lds, stream>>>(
            pool_p, pfw1, pfb1, fcb_p, 216, 1024, 1024, 0, nbA, gxA,
            pool_m, mfw1, mfb1, fcb_m, 312, 1024, 1024, 0, gxB);
    }
    // fused branch fc2 (no relu, K=1024, N=128 -> xc cols): MR=2, JT=32
    {
        int gxA = 128 / 32, nbA = gxA * (256 / 2);
        int gxB = gxA, nbB = nbA;
        size_t lds = (size_t)(2 * 1024 + 32 * 2 * 32) * sizeof(float);
        fc2_kernel<false, 2, 32><<<nbA + nbB, 256, lds, stream>>>(
            fcb_p, pfw2, pfb2, xc, 1024, 128, 256, 128, nbA, gxA,
            fcb_m, mfw2, mfb2, xc, 1024, 128, 256, 0, gxB);
    }

    // combined head
    {
        dim3 grid(1024 / 64, 256 / 4);
        size_t lds = (size_t)(4 * 256 + 16 * 4 * 64) * sizeof(float);
        fc_kernel<true, 4, 64><<<grid, 256, lds, stream>>>(xc, fc1w, fc1b, hb1, 256, 1024, 1024, 0);
    }
    {
        dim3 grid(512 / 64, 256 / 4);
        size_t lds = (size_t)(4 * 1024 + 16 * 4 * 64) * sizeof(float);
        fc_kernel<true, 4, 64><<<grid, 256, lds, stream>>>(hb1, fc2w, fc2b, hb2, 1024, 512, 512, 0);
    }
    matvec_kernel<<<256, 256, 0, stream>>>(hb2, outw, outb, out, 512);
}

// Round 18
// 444.859 us; speedup vs baseline: 1.1017x; 1.0148x over previous
//
#include <hip/hip_runtime.h>

// DGraphDTA r33 = r32 (451.4us) + 4-edge unroll in fused phase 1.
// r32 post-mortem: LDS halved but occ pinned at 17.5% -- grid is fully
// co-resident (1360 blocks <= capacity), so residency knobs are dead; the
// wall is per-thread latency chains. r21's 4-edge unroll was neutral at the
// fp32 byte ceiling (3.9 TB/s); r32 runs at 1.8 TB/s (latency regime) where
// doubled in-flight loads (4 idx + 4 norm + 8 rows) convert directly.
// fmaf order ascending-i preserved -> bitwise-identical (absmax 2.4e-4).

static inline int cdiv(int a, int b) { return (a + b - 1) / b; }

// ---------------- bf16 helpers ----------------

__device__ __forceinline__ unsigned short f2bf(float x) {
    unsigned u = __float_as_uint(x);
    u += 0x7FFFu + ((u >> 16) & 1u);   // RNE
    return (unsigned short)(u >> 16);
}
__device__ __forceinline__ float bf2f(unsigned short h) {
    return __uint_as_float((unsigned)h << 16);
}

// ---------------- fused CSR build ----------------

__global__ void deg2_kernel(const int* __restrict__ dstA, int* __restrict__ degA, int EA,
                            const int* __restrict__ dstB, int* __restrict__ degB, int EB) {
    int t = blockIdx.x * blockDim.x + threadIdx.x;
    if (t < EA) { atomicAdd(&degA[dstA[t]], 1); return; }
    t -= EA;
    if (t < EB) atomicAdd(&degB[dstB[t]], 1);
}

__global__ void degsum2_kernel(const int* __restrict__ deg_p, int NP, int nbp,
                               const int* __restrict__ deg_m, int NM, int* __restrict__ bsum) {
    __shared__ int s[256];
    int b = blockIdx.x, tid = threadIdx.x;
    const int* deg; int N, bi;
    if (b < nbp) { deg = deg_p; N = NP; bi = b; }
    else         { deg = deg_m; N = NM; bi = b - nbp; }
    int t = bi * 256 + tid;
    s[tid] = (t < N) ? deg[t] : 0;
    __syncthreads();
    for (int off = 128; off > 0; off >>= 1) {
        if (tid < off) s[tid] += s[tid + off];
        __syncthreads();
    }
    if (tid == 0) bsum[b] = s[0];
}

__global__ void scan2_kernel(int* __restrict__ bsum, int nbp, int nbm) {
    __shared__ int s[512];
    int tid = threadIdx.x;
    int total = nbp + nbm;
    int v = (tid < total) ? bsum[tid] : 0;
    bool isMol = (tid >= nbp);
    s[tid] = v;
    __syncthreads();
    for (int off = 1; off < 512; off <<= 1) {
        int x = 0;
        if (tid >= off) {
            int src = tid - off;
            if ((src >= nbp) == isMol) x = s[src];
        }
        __syncthreads();
        s[tid] += x;
        __syncthreads();
    }
    if (tid < total) bsum[tid] = s[tid] - v;
}

__global__ void alloc_scan2_kernel(const int* __restrict__ deg_p, int* rs_p, int* fc_p, float* n_p,
                                   int NP, int nbp,
                                   const int* __restrict__ deg_m, int* rs_m, int* fc_m, float* n_m,
                                   int NM, const int* __restrict__ bsum) {
    __shared__ int s[256];
    int b = blockIdx.x, tid = threadIdx.x;
    const int* deg; int* rs; int* fc; float* nrm; int N, bi;
    if (b < nbp) { deg = deg_p; rs = rs_p; fc = fc_p; nrm = n_p; N = NP; bi = b; }
    else         { deg = deg_m; rs = rs_m; fc = fc_m; nrm = n_m; N = NM; bi = b - nbp; }
    int t = bi * 256 + tid;
    int v = (t < N) ? deg[t] : 0;
    s[tid] = v;
    __syncthreads();
    for (int off = 1; off < 256; off <<= 1) {
        int x = (tid >= off) ? s[tid - off] : 0;
        __syncthreads();
        s[tid] += x;
        __syncthreads();
    }
    if (t < N) {
        int start = bsum[b] + s[tid] - v;
        rs[t] = start;
        fc[t] = start;
        nrm[t] = rsqrtf((float)v + 1.0f);
    }
}

__global__ void fill2_kernel(const int* srcA, const int* dstA, int* fcA, int* esA, int EA,
                             const int* srcB, const int* dstB, int* fcB, int* esB, int EB) {
    int t = blockIdx.x * blockDim.x + threadIdx.x;
    if (t < EA) { int p = atomicAdd(&fcA[dstA[t]], 1); esA[p] = srcA[t]; return; }
    t -= EA;
    if (t < EB) { int p = atomicAdd(&fcB[dstB[t]], 1); esB[p] = srcB[t]; }
}

__device__ __forceinline__ void gs_body(const int* batch, int* gs, int t, int N, int B) {
    int b = batch[t];
    int bp = (t == 0) ? -1 : batch[t - 1];
    for (int g = bp + 1; g <= b; ++g) gs[g] = t;
    if (t == N - 1) for (int g = b + 1; g <= B; ++g) gs[g] = N;
}

__global__ void gs2_kernel(const int* batchA, int* gsA, int NA,
                           const int* batchB, int* gsB, int NB, int B) {
    int t = blockIdx.x * blockDim.x + threadIdx.x;
    if (t < NA) { gs_body(batchA, gsA, t, NA, B); return; }
    t -= NA;
    if (t < NB) gs_body(batchB, gsB, t, NB, B);
}

// pad + convert x0 to bf16 rows
__global__ void pad2_kernel(const float* xA, unsigned short* yA, int NA, int FA, int SA,
                            const float* xB, unsigned short* yB, int NB, int FB, int SB) {
    int t = blockIdx.x * blockDim.x + threadIdx.x;
    if (t < NA * SA) {
        int r = t / SA, j = t - r * SA;
        yA[t] = (j < FA) ? f2bf(xA[(size_t)r * FA + j]) : (unsigned short)0;
        return;
    }
    t -= NA * SA;
    if (t < NB * SB) {
        int r = t / SB, j = t - r * SB;
        yB[t] = (j < FB) ? f2bf(xB[(size_t)r * FB + j]) : (unsigned short)0;
    }
}

// ---------------- W pack: transpose + pad + bf16 hi/lo split ----------------
//   seg offW    Kp   Np   K   N     offB
//   p1  0       64   64   54  54    0
//   p2  4096    64   128  54  108   64
//   p3  12288   128  256  108 216   192
//   m1  45056   96   128  78  78    448
//   m2  57344   128  192  78  156   576
//   m3  81920   192  320  156 312   768   (totals: 143360 W, 1088 bias)

__global__ void wpack_kernel(
    const float* __restrict__ w1p, const float* __restrict__ w2p, const float* __restrict__ w3p,
    const float* __restrict__ b1p, const float* __restrict__ b2p, const float* __restrict__ b3p,
    const float* __restrict__ w1m, const float* __restrict__ w2m, const float* __restrict__ w3m,
    const float* __restrict__ b1m, const float* __restrict__ b2m, const float* __restrict__ b3m,
    unsigned short* __restrict__ Wh, unsigned short* __restrict__ Wl, float* __restrict__ Bp)
{
    int t = blockIdx.x * 256 + threadIdx.x;
    if (t < 143360) {
        const float* w; int Kp, K, N, off;
        if      (t <  4096) { w = w1p; Kp = 64;  K = 54;  N = 54;  off = 0; }
        else if (t < 12288) { w = w2p; Kp = 64;  K = 54;  N = 108; off = 4096; }
        else if (t < 45056) { w = w3p; Kp = 128; K = 108; N = 216; off = 12288; }
        else if (t < 57344) { w = w1m; Kp = 96;  K = 78;  N = 78;  off = 45056; }
        else if (t < 81920) { w = w2m; Kp = 128; K = 78;  N = 156; off = 57344; }
        else                { w = w3m; Kp = 192; K = 156; N = 312; off = 81920; }
        int local = t - off;
        int n = local / Kp, k = local - n * Kp;
        float v = (k < K && n < N) ? w[(size_t)k * N + n] : 0.0f;
        unsigned short h = f2bf(v);
        Wh[t] = h;
        Wl[t] = f2bf(v - bf2f(h));
        return;
    }
    int u = t - 143360;
    if (u < 1088) {
        const float* b; int N, off;
        if      (u <  64) { b = b1p; N = 54;  off = 0; }
        else if (u < 192) { b = b2p; N = 108; off = 64; }
        else if (u < 448) { b = b3p; N = 216; off = 192; }
        else if (u < 576) { b = b1m; N = 78;  off = 448; }
        else if (u < 768) { b = b2m; N = 156; off = 576; }
        else              { b = b3m; N = 312; off = 768; }
        int n = u - off;
        Bp[u] = (n < N) ? b[n] : 0.0f;
    }
}

// ---------------- fused gather+GEMM (64 rows x full Np, bf16 A single-buffer) ----------------

typedef __attribute__((ext_vector_type(8))) short s16x8;
typedef __attribute__((ext_vector_type(4))) float f32x4_t;

template <int KP, int NPo>
__device__ __forceinline__ void fused_body(
    const unsigned short* __restrict__ X, const float* __restrict__ norm,
    const int* __restrict__ rs, const int* __restrict__ deg, const int* __restrict__ es,
    const unsigned short* __restrict__ Wh, const unsigned short* __restrict__ Wl,
    const float* __restrict__ bias, unsigned short* __restrict__ out,
    int brow, unsigned short* Ah)
{
    constexpr int LDK = KP + 8;   // shorts; row offset = 4 banks mod 32 -> <=2-way
    constexpr int UV  = KP / 8;   // ushort8 units per row
    constexpr int UV2 = UV / 2;   // 2-unit pieces per row
    constexpr int NF  = NPo / 64; // N-frags per wave
    const int tid = threadIdx.x;

    // ---- phase 1: aggregate 64 bf16 rows -> fp32 -> bf16 in LDS (4-edge unroll) ----
    const s16x8* xv = reinterpret_cast<const s16x8*>(X);
    for (int p = tid; p < 64 * UV2; p += 256) {
        int r = p / UV2, q = p - r * UV2;
        int n = brow + r;
        size_t base = (size_t)n * UV;
        float nn = norm[n];
        s16x8 u0 = xv[base + q], u1 = xv[base + q + UV2];
        float a0[8], a1[8];
#pragma unroll
        for (int k = 0; k < 8; ++k) {
            a0[k] = nn * bf2f((unsigned short)u0[k]);
            a1[k] = nn * bf2f((unsigned short)u1[k]);
        }
        int rsv = rs[n], d = deg[n];
        const int* e = es + rsv;
        int i = 0;
        for (; i + 4 <= d; i += 4) {
            int s0 = e[i], s1 = e[i + 1], s2 = e[i + 2], s3 = e[i + 3];
            float n0 = norm[s0], n1 = norm[s1], n2 = norm[s2], n3 = norm[s3];
            size_t b0 = (size_t)s0 * UV, b1 = (size_t)s1 * UV;
            size_t b2 = (size_t)s2 * UV, b3 = (size_t)s3 * UV;
            s16x8 v00 = xv[b0 + q], v01 = xv[b0 + q + UV2];
            s16x8 v10 = xv[b1 + q], v11 = xv[b1 + q + UV2];
            s16x8 v20 = xv[b2 + q], v21 = xv[b2 + q + UV2];
            s16x8 v30 = xv[b3 + q], v31 = xv[b3 + q + UV2];
#pragma unroll
            for (int k = 0; k < 8; ++k) {
                a0[k] = fmaf(n0, bf2f((unsigned short)v00[k]), a0[k]);
                a1[k] = fmaf(n0, bf2f((unsigned short)v01[k]), a1[k]);
            }
#pragma unroll
            for (int k = 0; k < 8; ++k) {
                a0[k] = fmaf(n1, bf2f((unsigned short)v10[k]), a0[k]);
                a1[k] = fmaf(n1, bf2f((unsigned short)v11[k]), a1[k]);
            }
#pragma unroll
            for (int k = 0; k < 8; ++k) {
                a0[k] = fmaf(n2, bf2f((unsigned short)v20[k]), a0[k]);
                a1[k] = fmaf(n2, bf2f((unsigned short)v21[k]), a1[k]);
            }
#pragma unroll
            for (int k = 0; k < 8; ++k) {
                a0[k] = fmaf(n3, bf2f((unsigned short)v30[k]), a0[k]);
                a1[k] = fmaf(n3, bf2f((unsigned short)v31[k]), a1[k]);
            }
        }
        for (; i + 2 <= d; i += 2) {
            int s0 = e[i], s1 = e[i + 1];
            float n0 = norm[s0], n1 = norm[s1];
            size_t b0 = (size_t)s0 * UV, b1 = (size_t)s1 * UV;
            s16x8 v00 = xv[b0 + q], v01 = xv[b0 + q + UV2];
            s16x8 v10 = xv[b1 + q], v11 = xv[b1 + q + UV2];
#pragma unroll
            for (int k = 0; k < 8; ++k) {
                a0[k] = fmaf(n0, bf2f((unsigned short)v00[k]), a0[k]);
                a1[k] = fmaf(n0, bf2f((unsigned short)v01[k]), a1[k]);
            }
#pragma unroll
            for (int k = 0; k < 8; ++k) {
                a0[k] = fmaf(n1, bf2f((unsigned short)v10[k]), a0[k]);
                a1[k] = fmaf(n1, bf2f((unsigned short)v11[k]), a1[k]);
            }
        }
        if (i < d) {
            int s0 = e[i];
            float n0 = norm[s0];
            size_t b0 = (size_t)s0 * UV;
            s16x8 v00 = xv[b0 + q], v01 = xv[b0 + q + UV2];
#pragma unroll
            for (int k = 0; k < 8; ++k) {
                a0[k] = fmaf(n0, bf2f((unsigned short)v00[k]), a0[k]);
                a1[k] = fmaf(n0, bf2f((unsigned short)v01[k]), a1[k]);
            }
        }
        s16x8 h0, h1;
#pragma unroll
        for (int k = 0; k < 8; ++k) {
            h0[k] = (short)f2bf(a0[k]);
            h1[k] = (short)f2bf(a1[k]);
        }
        *reinterpret_cast<s16x8*>(&Ah[r * LDK + 8 * q]) = h0;
        *reinterpret_cast<s16x8*>(&Ah[r * LDK + 8 * (q + UV2)]) = h1;
    }
    __syncthreads();

    // ---- phase 2: 2-term MFMA (A = bf16 agg; W = hi+lo) over all Np columns ----
    const int wave = tid >> 6, lane = tid & 63;
    const int l15 = lane & 15, l4 = lane >> 4;
    const int nc0 = wave * (NPo / 4);

    f32x4_t acc[4][NF];
#pragma unroll
    for (int mf = 0; mf < 4; ++mf)
#pragma unroll
        for (int nf = 0; nf < NF; ++nf)
            acc[mf][nf] = (f32x4_t){0.f, 0.f, 0.f, 0.f};

    for (int k0 = 0; k0 < KP; k0 += 32) {
        s16x8 ah[4];
#pragma unroll
        for (int mf = 0; mf < 4; ++mf) {
            int r = mf * 16 + l15;
            ah[mf] = *reinterpret_cast<const s16x8*>(&Ah[r * LDK + k0 + l4 * 8]);
        }
#pragma unroll
        for (int nf = 0; nf < NF; ++nf) {
            size_t wb = (size_t)(nc0 + nf * 16 + l15) * KP + k0 + l4 * 8;
            s16x8 bh = *reinterpret_cast<const s16x8*>(&Wh[wb]);
            s16x8 bl = *reinterpret_cast<const s16x8*>(&Wl[wb]);
#pragma unroll
            for (int mf = 0; mf < 4; ++mf) {
                acc[mf][nf] = __builtin_amdgcn_mfma_f32_16x16x32_bf16(ah[mf], bh, acc[mf][nf], 0, 0, 0);
                acc[mf][nf] = __builtin_amdgcn_mfma_f32_16x16x32_bf16(ah[mf], bl, acc[mf][nf], 0, 0, 0);
            }
        }
    }

    // epilogue: C frag col = lane&15, row = (lane>>4)*4 + reg; store bf16
#pragma unroll
    for (int mf = 0; mf < 4; ++mf) {
#pragma unroll
        for (int reg = 0; reg < 4; ++reg) {
            int gm = brow + mf * 16 + l4 * 4 + reg;
            float sc = norm[gm];
#pragma unroll
            for (int nf = 0; nf < NF; ++nf) {
                int gn = nc0 + nf * 16 + l15;
                float v = fmaxf(fmaf(sc, acc[mf][nf][reg], bias[gn]), 0.f);
                out[(size_t)gm * NPo + gn] = f2bf(v);
            }
        }
    }
}

template <int KPA, int NPA, int KPB, int NPB>
__global__ __launch_bounds__(256) void fused_gcn2_kernel(
    const unsigned short* XA, const float* nA, const int* rsA, const int* dA, const int* esA,
    const unsigned short* WhA, const unsigned short* WlA, const float* bsA,
    unsigned short* oA, int nbA,
    const unsigned short* XB, const float* nB, const int* rsB, const int* dB, const int* esB,
    const unsigned short* WhB, const unsigned short* WlB, const float* bsB,
    unsigned short* oB)
{
    constexpr int KMAX = (KPA > KPB ? KPA : KPB);
    __shared__ __align__(16) unsigned short Ah[64 * (KMAX + 8)];
    int bid = blockIdx.x;
    if (bid < nbA)
        fused_body<KPA, NPA>(XA, nA, rsA, dA, esA, WhA, WlA, bsA, oA, bid * 64, Ah);
    else
        fused_body<KPB, NPB>(XB, nB, rsB, dB, esB, WhB, WlB, bsB, oB, (bid - nbA) * 64, Ah);
}

// ---------------- vec helpers (fc path, fp32) ----------------

__device__ __forceinline__ float4 vmad(float s, float4 a, float4 b) {
    return make_float4(fmaf(s, a.x, b.x), fmaf(s, a.y, b.y), fmaf(s, a.z, b.z), fmaf(s, a.w, b.w));
}

// ---------------- FC (M=256): M-reuse + deep split-K ----------------

template <bool RELU, int MR, int JT>
__device__ __forceinline__ void fc_body(
    const float* __restrict__ X, const float* __restrict__ W,
    const float* __restrict__ bias, float* __restrict__ out,
    int K, int N, int out_stride, int out_off, int bx, int by, float* smem)
{
    constexpr int TJ = JT / 4;
    constexpr int SK = 256 / TJ;
    float* Xs = smem;
    float* red = smem + MR * K;

    const int tid = threadIdx.x;
    const int m0 = by * MR;
    const int j0 = bx * JT;

    for (int idx = tid; idx < MR * K; idx += 256) {
        int r = idx / K, k = idx - r * K;
        Xs[idx] = X[(size_t)(m0 + r) * K + k];
    }
    __syncthreads();

    const int tj = tid % TJ;
    const int s  = tid / TJ;
    const int chunk = (K + SK - 1) / SK;
    const int kb = s * chunk;
    const int ke = min(K, kb + chunk);

    const float4* w4 = reinterpret_cast<const float4*>(W + j0) + tj;
    const int wstride = N >> 2;

    float4 acc[MR];
#pragma unroll
    for (int r = 0; r < MR; ++r) acc[r] = make_float4(0.f, 0.f, 0.f, 0.f);
    for (int k = kb; k < ke; ++k) {
        float4 w = w4[(size_t)k * wstride];
#pragma unroll
        for (int r = 0; r < MR; ++r)
            acc[r] = vmad(Xs[r * K + k], w, acc[r]);
    }
#pragma unroll
    for (int r = 0; r < MR; ++r) {
        float* rr = red + ((s * MR + r) * JT) + tj * 4;
        rr[0] = acc[r].x; rr[1] = acc[r].y; rr[2] = acc[r].z; rr[3] = acc[r].w;
    }
    __syncthreads();

    for (int o = tid; o < MR * JT; o += 256) {
        int r = o / JT, j = o - r * JT;
        float v = 0.f;
#pragma unroll
        for (int ss = 0; ss < SK; ++ss) v += red[(ss * MR + r) * JT + j];
        v += bias[j0 + j];
        if (RELU) v = fmaxf(v, 0.0f);
        out[(size_t)(m0 + r) * out_stride + out_off + j0 + j] = v;
    }
}

template <bool RELU, int MR, int JT>
__global__ __launch_bounds__(256) void fc2_kernel(
    const float* XA, const float* WA, const float* bA, float* oA,
    int KA, int NA, int osA, int ooA, int nbA, int gxA,
    const float* XB, const float* WB, const float* bB, float* oB,
    int KB, int NB, int osB, int ooB, int gxB)
{
    extern __shared__ float smem[];
    int bid = blockIdx.x;
    if (bid < nbA) {
        fc_body<RELU, MR, JT>(XA, WA, bA, oA, KA, NA, osA, ooA, bid % gxA, bid / gxA, smem);
    } else {
        bid -= nbA;
        fc_body<RELU, MR, JT>(XB, WB, bB, oB, KB, NB, osB, ooB, bid % gxB, bid / gxB, smem);
    }
}

template <bool RELU, int MR, int JT>
__global__ __launch_bounds__(256) void fc_kernel(
    const float* X, const float* W, const float* b, float* o,
    int K, int N, int out_stride, int out_off)
{
    extern __shared__ float smem[];
    fc_body<RELU, MR, JT>(X, W, b, o, K, N, out_stride, out_off, blockIdx.x, blockIdx.y, smem);
}

// final layer: one block per row, 256 threads, LDS tree reduce (K=512)
__global__ __launch_bounds__(256) void matvec_kernel(
    const float* __restrict__ X, const float* __restrict__ W,
    const float* __restrict__ bias, float* __restrict__ out, int K)
{
    __shared__ float red[256];
    const int m = blockIdx.x;
    const int tid = threadIdx.x;
    float acc = 0.f;
    for (int k = tid; k < K; k += 256) acc = fmaf(X[(size_t)m * K + k], W[k], acc);
    red[tid] = acc;
    __syncthreads();
    for (int w = 128; w >= 64; w >>= 1) {
        if (tid < w) red[tid] += red[tid + w];
        __syncthreads();
    }
    if (tid < 64) {
        float v = red[tid];
        for (int off = 32; off > 0; off >>= 1) v += __shfl_down(v, off, 64);
        if (tid == 0) out[m] = v + bias[0];
    }
}

// ---------------- row-parallel pooling (block per graph, bf16 input) ----------------
// pro: U=27 ushort8 units (216 elems), stride 32 units; mol: U=39, stride 40.

__global__ __launch_bounds__(1024) void pool4_kernel(
    const unsigned short* __restrict__ xA, const int* __restrict__ gsA, float* __restrict__ poolA,
    const unsigned short* __restrict__ xB, const int* __restrict__ gsB, float* __restrict__ poolB)
{
    __shared__ float red[1024 * 8];
    const int b = blockIdx.x, tid = threadIdx.x;
    const s16x8* xv; const int* gs; float* pool; int U, sv, g;
    if (b < 256) { xv = (const s16x8*)xA; gs = gsA; pool = poolA; U = 27; sv = 32; g = b; }
    else         { xv = (const s16x8*)xB; gs = gsB; pool = poolB; U = 39; sv = 40; g = b - 256; }
    const int s = gs[g], c = gs[g + 1] - s;
    const int nrg = 1024 / U;
    const int jv = tid % U, rg = tid / U;

    float a[8] = {0.f, 0.f, 0.f, 0.f, 0.f, 0.f, 0.f, 0.f};
    if (rg < nrg) {
        for (int i = rg; i < c; i += nrg) {
            s16x8 u = xv[(size_t)(s + i) * sv + jv];
#pragma unroll
            for (int k = 0; k < 8; ++k) a[k] += bf2f((unsigned short)u[k]);
        }
    }
#pragma unroll
    for (int k = 0; k < 8; ++k) red[tid * 8 + k] = a[k];
    __syncthreads();
    if (rg == 0) {
        for (int q = 1; q < nrg; ++q) {
            const float* rr = &red[(q * U + jv) * 8];
#pragma unroll
            for (int k = 0; k < 8; ++k) a[k] += rr[k];
        }
        const float fc_ = (float)max(c, 1);
        float* po = &pool[(size_t)g * (U * 8) + jv * 8];
#pragma unroll
        for (int k = 0; k < 8; ++k) po[k] = a[k] / fc_;
    }
}

extern "C" void kernel_launch(void* const* d_in, const int* in_sizes, int n_in,
                              void* d_out, int out_size, void* d_ws, size_t ws_size,
                              hipStream_t stream) {
    const float* mol_x     = (const float*)d_in[0];
    const int*   mol_ei    = (const int*)  d_in[1];
    const int*   mol_batch = (const int*)  d_in[2];
    const float* pro_x     = (const float*)d_in[3];
    const int*   pro_ei    = (const int*)  d_in[4];
    const int*   pro_batch = (const int*)  d_in[5];
    const float* mw1 = (const float*)d_in[6],  * mb1 = (const float*)d_in[7];
    const float* mw2 = (const float*)d_in[8],  * mb2 = (const float*)d_in[9];
    const float* mw3 = (const float*)d_in[10], * mb3 = (const float*)d_in[11];
    const float* mfw1 = (const float*)d_in[12], * mfb1 = (const float*)d_in[13];
    const float* mfw2 = (const float*)d_in[14], * mfb2 = (const float*)d_in[15];
    const float* pw1 = (const float*)d_in[16], * pb1 = (const float*)d_in[17];
    const float* pw2 = (const float*)d_in[18], * pb2 = (const float*)d_in[19];
    const float* pw3 = (const float*)d_in[20], * pb3 = (const float*)d_in[21];
    const float* pfw1 = (const float*)d_in[22], * pfb1 = (const float*)d_in[23];
    const float* pfw2 = (const float*)d_in[24], * pfb2 = (const float*)d_in[25];
    const float* fc1w = (const float*)d_in[26], * fc1b = (const float*)d_in[27];
    const float* fc2w = (const float*)d_in[28], * fc2b = (const float*)d_in[29];
    const float* outw = (const float*)d_in[30], * outb = (const float*)d_in[31];
    float* out = (float*)d_out;

    // ---- dims ----
    const int NP = 76800, EP = 768000;
    const int NM = 10240, EM = 40960;
    const int NBP = cdiv(NP, 256), NBM = cdiv(NM, 256);  // 300, 40
    // padded dims: pro Kp {64,64,128} Np {64,128,256}; mol Kp {96,128,192} Np {128,192,320}

    // ---- workspace layout (bf16 activations) ----
    unsigned short* Pp = (unsigned short*)d_ws;       // 76800*256
    unsigned short* Rp = Pp + (size_t)76800 * 256;    // 76800*128
    unsigned short* Pm = Rp + (size_t)76800 * 128;    // 10240*320
    unsigned short* Rm = Pm + (size_t)10240 * 320;    // 10240*192
    unsigned short* WpkH = Rm + (size_t)10240 * 192;  // 143360
    unsigned short* WpkL = WpkH + 143360;             // 143360
    float* Bpk    = (float*)(WpkL + 143360);          // 1088
    float* norm_p = Bpk + 1088;                       // 76800
    float* norm_m = norm_p + NP;                      // 10240
    float* pool_p = norm_m + NM;                      // 256*216
    float* pool_m = pool_p + 256 * 216;               // 256*312
    float* fcb_p  = pool_m + 256 * 312;               // 256*1024
    float* fcb_m  = fcb_p + 256 * 1024;               // 256*1024
    float* xc     = fcb_m + 256 * 1024;               // 256*256
    float* hb1    = xc + 256 * 256;                   // 256*1024
    float* hb2    = hb1 + 256 * 1024;                 // 256*512
    int* ibase    = (int*)(hb2 + 256 * 512);
    int* deg_p = ibase;                        // 76800 (memset region start)
    int* deg_m = deg_p + NP;                   // 10240
    int* rs_p  = deg_m + NM;                   // 76800
    int* fc_p  = rs_p + NP;                    // 76800
    int* es_p  = fc_p + NP;                    // 768000
    int* rs_m  = es_p + EP;                    // 10240
    int* fc_m  = rs_m + NM;                    // 10240
    int* es_m  = fc_m + NM;                    // 40960
    int* gs_p  = es_m + EM;                    // 257 (+pad)
    int* gs_m  = gs_p + 260;                   // 257 (+pad)
    int* bsum  = gs_m + 260;                   // 384 (NBP+NBM=340)

    const int BLK = 256;

    // ---- fused CSR build + W pack ----
    hipMemsetAsync(deg_p, 0, (size_t)(NP + NM) * sizeof(int), stream);
    deg2_kernel<<<cdiv(EP + EM, BLK), BLK, 0, stream>>>(pro_ei + EP, deg_p, EP, mol_ei + EM, deg_m, EM);
    degsum2_kernel<<<NBP + NBM, 256, 0, stream>>>(deg_p, NP, NBP, deg_m, NM, bsum);
    scan2_kernel<<<1, 512, 0, stream>>>(bsum, NBP, NBM);
    alloc_scan2_kernel<<<NBP + NBM, 256, 0, stream>>>(deg_p, rs_p, fc_p, norm_p, NP, NBP,
                                                      deg_m, rs_m, fc_m, norm_m, NM, bsum);
    fill2_kernel<<<cdiv(EP + EM, BLK), BLK, 0, stream>>>(pro_ei, pro_ei + EP, fc_p, es_p, EP,
                                                         mol_ei, mol_ei + EM, fc_m, es_m, EM);
    gs2_kernel<<<cdiv(NP + NM, BLK), BLK, 0, stream>>>(pro_batch, gs_p, NP, mol_batch, gs_m, NM, 256);
    pad2_kernel<<<cdiv(NP * 64 + NM * 96, BLK), BLK, 0, stream>>>(pro_x, Rp, NP, 54, 64,
                                                                  mol_x, Rm, NM, 78, 96);
    wpack_kernel<<<cdiv(143360 + 1088, 256), 256, 0, stream>>>(
        pw1, pw2, pw3, pb1, pb2, pb3, mw1, mw2, mw3, mb1, mb2, mb3, WpkH, WpkL, Bpk);

    const int NB_P = NP / 64;   // 1200
    const int NB_M = NM / 64;   // 160

    // L1: R(x0 pad) -> P
    fused_gcn2_kernel<64, 64, 96, 128><<<NB_P + NB_M, 256, 0, stream>>>(
        Rp, norm_p, rs_p, deg_p, es_p, WpkH + 0, WpkL + 0, Bpk + 0, Pp, NB_P,
        Rm, norm_m, rs_m, deg_m, es_m, WpkH + 45056, WpkL + 45056, Bpk + 448, Pm);
    // L2: P -> R
    fused_gcn2_kernel<64, 128, 128, 192><<<NB_P + NB_M, 256, 0, stream>>>(
        Pp, norm_p, rs_p, deg_p, es_p, WpkH + 4096, WpkL + 4096, Bpk + 64, Rp, NB_P,
        Pm, norm_m, rs_m, deg_m, es_m, WpkH + 57344, WpkL + 57344, Bpk + 576, Rm);
    // L3: R -> P
    fused_gcn2_kernel<128, 256, 192, 320><<<NB_P + NB_M, 256, 0, stream>>>(
        Rp, norm_p, rs_p, deg_p, es_p, WpkH + 12288, WpkL + 12288, Bpk + 192, Pp, NB_P,
        Rm, norm_m, rs_m, deg_m, es_m, WpkH + 81920, WpkL + 81920, Bpk + 768, Pm);

    // row-parallel pool (bf16 in, fp32 compact out)
    pool4_kernel<<<512, 1024, 0, stream>>>(Pp, gs_p, pool_p, Pm, gs_m, pool_m);

    // fused branch fc1 (relu, K=216/312, N=1024): MR=4, JT=64; LDS sized for K=312
    {
        int gxA = 1024 / 64, nbA = gxA * (256 / 4);
        int gxB = 1024 / 64, nbB = gxB * (256 / 4);
        size_t lds = (size_t)(4 * 312 + 16 * 4 * 64) * sizeof(float);
        fc2_kernel<true, 4, 64><<<nbA + nbB, 256, lds, stream>>>(
            pool_p, pfw1, pfb1, fcb_p, 216, 1024, 1024, 0, nbA, gxA,
            pool_m, mfw1, mfb1, fcb_m, 312, 1024, 1024, 0, gxB);
    }
    // fused branch fc2 (no relu, K=1024, N=128 -> xc cols): MR=2, JT=32
    {
        int gxA = 128 / 32, nbA = gxA * (256 / 2);
        int gxB = gxA, nbB = nbA;
        size_t lds = (size_t)(2 * 1024 + 32 * 2 * 32) * sizeof(float);
        fc2_kernel<false, 2, 32><<<nbA + nbB, 256, lds, stream>>>(
            fcb_p, pfw2, pfb2, xc, 1024, 128, 256, 128, nbA, gxA,
            fcb_m, mfw2, mfb2, xc, 1024, 128, 256, 0, gxB);
    }

    // combined head
    {
        dim3 grid(1024 / 64, 256 / 4);
        size_t lds = (size_t)(4 * 256 + 16 * 4 * 64) * sizeof(float);
        fc_kernel<true, 4, 64><<<grid, 256, lds, stream>>>(xc, fc1w, fc1b, hb1, 256, 1024, 1024, 0);
    }
    {
        dim3 grid(512 / 64, 256 / 4);
        size_t lds = (size_t)(4 * 1024 + 16 * 4 * 64) * sizeof(float);
        fc_kernel<true, 4, 64><<<grid, 256, lds, stream>>>(hb1, fc2w, fc2b, hb2, 1024, 512, 512, 0);
    }
    matvec_kernel<<<256, 256, 0, stream>>>(hb2, outw, outb, out, 512);
}